// Round 5
// baseline (541.284 us; speedup 1.0000x reference)
//
#include <hip/hip_runtime.h>
#include <hip/hip_bf16.h>
#include <math.h>

// RaffelAttention round 5.
// attn: swapped QK^T, K/V streamed from L2 to registers (no K/V LDS, no
// barriers), per-wave swizzled Ps tile for dense coalesced P stores.

#define Bc 2
#define Lc 2048
#define Dc 1024
#define Hc 16
#define Mc (Bc*Lc)
#define NT 32

typedef __attribute__((ext_vector_type(8))) __bf16 bf16x8;
typedef __attribute__((ext_vector_type(4))) float f32x4;
typedef __attribute__((ext_vector_type(16))) float f32x16;
typedef __attribute__((ext_vector_type(2))) unsigned u32x2;

union U4 { unsigned u[4]; bf16x8 v; };

__device__ __forceinline__ void gl_lds16(const void* g, void* l) {
    __builtin_amdgcn_global_load_lds(
        (const __attribute__((address_space(1))) void*)g,
        (__attribute__((address_space(3))) void*)l, 16, 0, 0);
}
__device__ __forceinline__ unsigned pkbf(float a, float b) {
    unsigned short ua = __builtin_bit_cast(unsigned short, (__bf16)a);
    unsigned short ub = __builtin_bit_cast(unsigned short, (__bf16)b);
    return (unsigned)ua | ((unsigned)ub << 16);
}
__device__ __forceinline__ float lo2f(unsigned u){ return __builtin_bit_cast(float, u << 16); }
__device__ __forceinline__ float hi2f(unsigned u){ return __builtin_bit_cast(float, u & 0xffff0000u); }

#define WAIT_VM0 asm volatile("s_waitcnt vmcnt(0)" ::: "memory")

// ---------------------------------------------------------------------------
// prep: transpose weights to bf16 [n][k].  z=0..3 -> Wt[z]; z=4 -> Woh/Wol.
// ---------------------------------------------------------------------------
__global__ __launch_bounds__(256) void prep_kernel(
    const float* __restrict__ Wcq, const float* __restrict__ Wck,
    const float* __restrict__ Wpq, const float* __restrict__ Wpk,
    const float* __restrict__ Wo,
    __bf16* __restrict__ Wt, __bf16* __restrict__ Woh, __bf16* __restrict__ Wol)
{
    const int z = blockIdx.z;
    const float* W = (z==0)?Wcq:(z==1)?Wck:(z==2)?Wpq:(z==3)?Wpk:Wo;
    const int t = threadIdx.x;
    const int n  = blockIdx.x*64 + (t & 63);
    const int k0 = blockIdx.y*128 + (t >> 6)*32;
    float v[32];
    #pragma unroll
    for (int j = 0; j < 32; ++j) v[j] = W[(size_t)(k0+j)*Dc + n];
    if (z < 4) {
        __bf16* dst = Wt + (size_t)z*Dc*Dc + (size_t)n*Dc + k0;
        #pragma unroll
        for (int c = 0; c < 4; ++c) {
            bf16x8 o;
            #pragma unroll
            for (int j = 0; j < 8; ++j) o[j] = (__bf16)v[c*8+j];
            *(bf16x8*)(dst + c*8) = o;
        }
    } else {
        __bf16* dh = Woh + (size_t)n*Dc + k0;
        __bf16* dl = Wol + (size_t)n*Dc + k0;
        #pragma unroll
        for (int c = 0; c < 4; ++c) {
            bf16x8 oh, ol;
            #pragma unroll
            for (int j = 0; j < 8; ++j) {
                float x = v[c*8+j];
                __bf16 hi = (__bf16)x;
                oh[j] = hi; ol[j] = (__bf16)(x - (float)hi);
            }
            *(bf16x8*)(dh + c*8) = oh;
            *(bf16x8*)(dl + c*8) = ol;
        }
    }
}

// ---------------------------------------------------------------------------
// proj: X(fp32) @ Wt[z](bf16,[n][k]) -> Q'/K' bf16 [B,H,L,128] halves.
// ---------------------------------------------------------------------------
__global__ __launch_bounds__(256) void proj_kernel(
    const float* __restrict__ hidden, const float* __restrict__ pos,
    const __bf16* __restrict__ Wt,
    const float* __restrict__ bcq, const float* __restrict__ bck,
    const float* __restrict__ bpq, const float* __restrict__ bpk,
    __bf16* __restrict__ Qc, __bf16* __restrict__ Kc)
{
    const int g = blockIdx.x;
    const int nblk = g >> 7, sg = g & 127, mblk = sg & 31, z = sg >> 5;
    const int m0 = mblk*128, n0 = nblk*128;
    const float* X = (z < 2) ? hidden : pos;
    const __bf16* Wz = Wt + (size_t)z*Dc*Dc;
    const float* bias = (z==0)?bcq:(z==1)?bck:(z==2)?bpq:bpk;
    __bf16* dst = (z & 1) ? Kc : Qc;
    const int half = z >> 1;
    const float scale = (z & 1) ? 1.0f : 0.18033688011112042f; // 0.125*log2e on Q

    const int t = threadIdx.x, lane = t & 63, w = t >> 6;
    const int wm = w >> 1, wn = w & 1;

    __shared__ __align__(16) float  Asf[128][32];
    __shared__ __align__(16) __bf16 Bs[128][32];

    const int arowL = lane >> 3;
    const int acol  = ((lane & 7) ^ arowL) * 4;
    const int brow4 = lane >> 2;
    const int bcol  = ((lane & 3) ^ (brow4 & 3)) * 8;

    f32x4 acc[4][4] = {};

    for (int k0 = 0; k0 < Dc; k0 += 32) {
        #pragma unroll
        for (int i = 0; i < 4; ++i) {
            int row = 8*(4*w+i) + arowL;
            gl_lds16(X + (size_t)(m0+row)*Dc + k0 + acol, (char*)Asf + (4*w+i)*1024);
        }
        #pragma unroll
        for (int i = 0; i < 2; ++i) {
            int row = 16*(2*w+i) + brow4;
            gl_lds16(Wz + (size_t)(n0+row)*Dc + k0 + bcol, (char*)Bs + (2*w+i)*1024);
        }
        WAIT_VM0; __syncthreads();
        bf16x8 a[4], b[4];
        const int s2 = lane >> 4;
        #pragma unroll
        for (int i = 0; i < 4; ++i) {
            int R = wm*64 + i*16 + (lane&15);
            f32x4 x0 = *(const f32x4*)((const char*)&Asf[R][0] + (((2*s2  ) ^ (R&7))*16));
            f32x4 x1 = *(const f32x4*)((const char*)&Asf[R][0] + (((2*s2+1) ^ (R&7))*16));
            bf16x8 af;
            af[0]=(__bf16)x0[0]; af[1]=(__bf16)x0[1]; af[2]=(__bf16)x0[2]; af[3]=(__bf16)x0[3];
            af[4]=(__bf16)x1[0]; af[5]=(__bf16)x1[1]; af[6]=(__bf16)x1[2]; af[7]=(__bf16)x1[3];
            a[i] = af;
            int Rb = wn*64 + i*16 + (lane&15);
            b[i] = *(const bf16x8*)((const char*)&Bs[Rb][0] + ((s2 ^ (Rb&3))*16));
        }
        #pragma unroll
        for (int mi = 0; mi < 4; ++mi)
            #pragma unroll
            for (int ni = 0; ni < 4; ++ni)
                acc[mi][ni] = __builtin_amdgcn_mfma_f32_16x16x32_bf16(a[mi], b[ni], acc[mi][ni], 0, 0, 0);
        __syncthreads();
    }
    #pragma unroll
    for (int mi = 0; mi < 4; ++mi)
        #pragma unroll
        for (int ni = 0; ni < 4; ++ni)
            #pragma unroll
            for (int r = 0; r < 4; ++r) {
                int row = m0 + wm*64 + mi*16 + (lane>>4)*4 + r;
                int col = n0 + wn*64 + ni*16 + (lane&15);
                float v = (acc[mi][ni][r] + bias[col]) * scale;
                int bb = row >> 11, l = row & (Lc-1);
                int hh = col >> 6,  hd = col & 63;
                dst[(((size_t)bb*Hc + hh)*Lc + l)*128 + half*64 + hd] = (__bf16)v;
            }
}

// ---------------------------------------------------------------------------
// vt: VT[bh][d 0..63][l 0..2047] = Kc[bh][l][d]  (V = ck = first 64 dims)
// ---------------------------------------------------------------------------
__global__ __launch_bounds__(256) void vt_kernel(
    const __bf16* __restrict__ Kc, __bf16* __restrict__ VT)
{
    const int l0 = blockIdx.x * 128, hb = blockIdx.y;
    const int t = threadIdx.x, w = t >> 6, lane = t & 63;
    __shared__ __bf16 T[128][72];
    const __bf16* src = Kc + ((size_t)hb*Lc + l0)*128;
    {
        const int lr = t >> 3, cc = t & 7;
        #pragma unroll
        for (int j = 0; j < 4; ++j)
            *(bf16x8*)&T[lr + j*32][cc*8] = *(const bf16x8*)(src + (size_t)(lr + j*32)*128 + cc*8);
    }
    __syncthreads();
    {
        const int d = lane;
        __bf16* dstp = VT + ((size_t)hb*64 + d)*Lc + l0 + w*32;
        #pragma unroll
        for (int j = 0; j < 4; ++j) {
            bf16x8 o;
            #pragma unroll
            for (int i = 0; i < 8; ++i) o[i] = T[w*32 + j*8 + i][d];
            *(bf16x8*)(dstp + j*8) = o;
        }
    }
}

// ---------------------------------------------------------------------------
// attn: per (b,h,128-row q-tile). 4 independent waves, 32x32x16 MFMA.
// K/V streamed L2->regs. No barriers. Per-wave swizzled Ps for P stores.
// ---------------------------------------------------------------------------
__global__ __launch_bounds__(256) void attn_kernel(
    const __bf16* __restrict__ Qc, const __bf16* __restrict__ Kc,
    const __bf16* __restrict__ VT, const float* __restrict__ rel_bias,
    float* __restrict__ attn, __bf16* __restrict__ ctxh)
{
    const int g = blockIdx.x;
    const int qt = g >> 5, hb = g & 31, h = hb & 15, bb = hb >> 4;
    const int q0 = qt * 128;
    const int t = threadIdx.x, lane = t & 63, w = t >> 6;
    const int ln31 = lane & 31, hi = lane >> 5;

    const __bf16* Qp = Qc + (size_t)hb * Lc * 128;
    const __bf16* Kp = Kc + (size_t)hb * Lc * 128;
    const __bf16* Vp = VT + (size_t)hb * 64 * Lc;

    __shared__ __align__(16) char PsAll[4][4096];   // per-wave 32 x 128B, swizzled
    char* const PsW = PsAll[w];

    // Q fragments (B operand): col = q = ln31, k = ks*16 + hi*8
    bf16x8 qa[8];
    {
        const __bf16* qrow = Qp + (size_t)(q0 + w*32 + ln31) * 128 + hi*8;
        #pragma unroll
        for (int ks = 0; ks < 8; ++ks) qa[ks] = *(const bf16x8*)(qrow + ks*16);
    }

    const float bc = rel_bias[h] * 0.18033688011112042f;

    // ---------------- pass 1: per-lane scalar sumexp
    float lsum = 0.f;
    for (int kt = 0; kt < NT; ++kt) {
        const __bf16* kb = Kp + (size_t)kt*64*128 + hi*8;
        bf16x8 ka0[8], ka1[8];
        #pragma unroll
        for (int ks = 0; ks < 8; ++ks) {
            ka0[ks] = *(const bf16x8*)(kb + (size_t)ln31*128      + ks*16);
            ka1[ks] = *(const bf16x8*)(kb + (size_t)(32+ln31)*128 + ks*16);
        }
        f32x16 s0 = {}, s1 = {};
        #pragma unroll
        for (int ks = 0; ks < 8; ++ks) {
            s0 = __builtin_amdgcn_mfma_f32_32x32x16_bf16(ka0[ks], qa[ks], s0, 0, 0, 0);
            s1 = __builtin_amdgcn_mfma_f32_32x32x16_bf16(ka1[ks], qa[ks], s1, 0, 0, 0);
        }
        #pragma unroll
        for (int r = 0; r < 16; ++r)
            lsum += exp2f(s0[r] + bc) + exp2f(s1[r] + bc);
    }
    lsum += __shfl_xor(lsum, 32);
    const float badd = bc - log2f(lsum);

    // ---------------- pass 2: P out + PV
    f32x16 ctx0 = {}, ctx1 = {};
    float* abase = attn + ((size_t)hb*Lc + q0 + w*32)*Lc;
    const int rr = lane >> 4;     // store path: 0..3
    const int s8 = lane & 15;

    for (int kt = 0; kt < NT; ++kt) {
        const __bf16* kb = Kp + (size_t)kt*64*128 + hi*8;
        bf16x8 ka0[8], ka1[8];
        #pragma unroll
        for (int ks = 0; ks < 8; ++ks) {
            ka0[ks] = *(const bf16x8*)(kb + (size_t)ln31*128      + ks*16);
            ka1[ks] = *(const bf16x8*)(kb + (size_t)(32+ln31)*128 + ks*16);
        }
        const __bf16* vb = Vp + kt*64 + hi*8;
        bf16x8 va0[4], va1[4];
        #pragma unroll
        for (int ks = 0; ks < 4; ++ks) {
            va0[ks] = *(const bf16x8*)(vb + (size_t)ln31*Lc      + ks*16);
            va1[ks] = *(const bf16x8*)(vb + (size_t)(32+ln31)*Lc + ks*16);
        }
        f32x16 s0 = {}, s1 = {};
        #pragma unroll
        for (int ks = 0; ks < 8; ++ks) {
            s0 = __builtin_amdgcn_mfma_f32_32x32x16_bf16(ka0[ks], qa[ks], s0, 0, 0, 0);
            s1 = __builtin_amdgcn_mfma_f32_32x32x16_bf16(ka1[ks], qa[ks], s1, 0, 0, 0);
        }
        // p = exp2(s + badd); pack pairs; exchange hi/lo kv halves
        unsigned u0[8], u1[8], r0[8], r1[8];
        #pragma unroll
        for (int gq = 0; gq < 4; ++gq) {
            u0[gq]   = pkbf(exp2f(s0[4*gq+0]+badd), exp2f(s0[4*gq+1]+badd));
            u1[gq]   = pkbf(exp2f(s0[4*gq+2]+badd), exp2f(s0[4*gq+3]+badd));
            u0[4+gq] = pkbf(exp2f(s1[4*gq+0]+badd), exp2f(s1[4*gq+1]+badd));
            u1[4+gq] = pkbf(exp2f(s1[4*gq+2]+badd), exp2f(s1[4*gq+3]+badd));
        }
        #pragma unroll
        for (int gq = 0; gq < 8; ++gq) {
            r0[gq] = __shfl_xor(u0[gq], 32);
            r1[gq] = __shfl_xor(u1[gq], 32);
        }
        // assemble PV A-fragments (kv ascending); stage into per-wave Ps
        bf16x8 pb[4];
        #pragma unroll
        for (int ks = 0; ks < 4; ++ks) {
            const int gq = 2*ks + hi;
            U4 u;
            u.u[0] = hi ? r0[gq] : u0[gq];
            u.u[1] = hi ? r1[gq] : u1[gq];
            u.u[2] = hi ? u0[gq] : r0[gq];
            u.u[3] = hi ? u1[gq] : r1[gq];
            pb[ks] = u.v;
            *(bf16x8*)(PsW + ln31*128 + ((gq ^ (ln31 & 7))*16)) = u.v;
        }
        #pragma unroll
        for (int ks = 0; ks < 4; ++ks) {
            ctx0 = __builtin_amdgcn_mfma_f32_32x32x16_bf16(pb[ks], va0[ks], ctx0, 0, 0, 0);
            ctx1 = __builtin_amdgcn_mfma_f32_32x32x16_bf16(pb[ks], va1[ks], ctx1, 0, 0, 0);
        }
        // dense coalesced P stores: each instr = 4 rows x 256B contiguous
        #pragma unroll
        for (int j = 0; j < 8; ++j) {
            const int row = j*4 + rr;
            u32x2 d = *(const u32x2*)(PsW + row*128 + (((s8>>1) ^ (row&7))*16) + (s8&1)*8);
            f32x4 o;
            o[0]=lo2f(d[0]); o[1]=hi2f(d[0]); o[2]=lo2f(d[1]); o[3]=hi2f(d[1]);
            *(f32x4*)(abase + (size_t)row*Lc + kt*64 + s8*4) = o;
        }
    }

    #pragma unroll
    for (int r = 0; r < 16; ++r) {
        const int R = (r&3) + 8*(r>>2) + 4*hi;
        const size_t row = (size_t)bb*Lc + q0 + w*32 + R;
        ctxh[row*Dc + h*64 + ln31]      = (__bf16)ctx0[r];
        ctxh[row*Dc + h*64 + 32 + ln31] = (__bf16)ctx1[r];
    }
}

// ---------------------------------------------------------------------------
// out: ctxh(bf16) @ Wo + bo, B split hi/lo.  m97-style gload_lds + swizzle.
// ---------------------------------------------------------------------------
__global__ __launch_bounds__(256) void out_kernel(
    const __bf16* __restrict__ ctxh, const __bf16* __restrict__ Woh,
    const __bf16* __restrict__ Wol, const float* __restrict__ bo,
    float* __restrict__ out)
{
    const int m0 = blockIdx.y * 128, n0 = blockIdx.x * 128;
    const int t = threadIdx.x, lane = t & 63, w = t >> 6;
    const int wm = w >> 1, wn = w & 1;

    __shared__ __align__(16) __bf16 As[128][32];
    __shared__ __align__(16) __bf16 Bh[128][32];
    __shared__ __align__(16) __bf16 Bl[128][32];

    const int row4 = lane >> 2;
    const int scol = ((lane & 3) ^ (row4 & 3)) * 8;

    f32x4 acc[4][4] = {};

    for (int k0 = 0; k0 < Dc; k0 += 32) {
        #pragma unroll
        for (int i = 0; i < 2; ++i) {
            int row = 16*(2*w+i) + row4;
            gl_lds16(ctxh + (size_t)(m0+row)*Dc + k0 + scol, (char*)As + (2*w+i)*1024);
            gl_lds16(Woh  + (size_t)(n0+row)*Dc + k0 + scol, (char*)Bh + (2*w+i)*1024);
            gl_lds16(Wol  + (size_t)(n0+row)*Dc + k0 + scol, (char*)Bl + (2*w+i)*1024);
        }
        WAIT_VM0; __syncthreads();
        bf16x8 a[4], bh[4], bl[4];
        const int s2 = lane >> 4;
        #pragma unroll
        for (int i = 0; i < 4; ++i) {
            int Ra = wm*64 + i*16 + (lane&15);
            int Rb = wn*64 + i*16 + (lane&15);
            a[i]  = *(const bf16x8*)((const char*)&As[Ra][0] + ((s2 ^ (Ra&3))*16));
            bh[i] = *(const bf16x8*)((const char*)&Bh[Rb][0] + ((s2 ^ (Rb&3))*16));
            bl[i] = *(const bf16x8*)((const char*)&Bl[Rb][0] + ((s2 ^ (Rb&3))*16));
        }
        #pragma unroll
        for (int mi = 0; mi < 4; ++mi)
            #pragma unroll
            for (int ni = 0; ni < 4; ++ni) {
                acc[mi][ni] = __builtin_amdgcn_mfma_f32_16x16x32_bf16(a[mi], bh[ni], acc[mi][ni], 0, 0, 0);
                acc[mi][ni] = __builtin_amdgcn_mfma_f32_16x16x32_bf16(a[mi], bl[ni], acc[mi][ni], 0, 0, 0);
            }
        __syncthreads();
    }
    #pragma unroll
    for (int mi = 0; mi < 4; ++mi)
        #pragma unroll
        for (int ni = 0; ni < 4; ++ni)
            #pragma unroll
            for (int r = 0; r < 4; ++r) {
                int row = m0 + wm*64 + mi*16 + (lane>>4)*4 + r;
                int col = n0 + wn*64 + ni*16 + (lane&15);
                out[(size_t)row * Dc + col] = acc[mi][ni][r] + bo[col];
            }
}

// ---------------------------------------------------------------------------
extern "C" void kernel_launch(void* const* d_in, const int* in_sizes, int n_in,
                              void* d_out, int out_size, void* d_ws, size_t ws_size,
                              hipStream_t stream)
{
    const float* hidden = (const float*)d_in[0];
    const float* pos    = (const float*)d_in[1];
    const float* Wcq = (const float*)d_in[2];  const float* bcq = (const float*)d_in[3];
    const float* Wck = (const float*)d_in[4];  const float* bck = (const float*)d_in[5];
    const float* Wpq = (const float*)d_in[6];  const float* bpq = (const float*)d_in[7];
    const float* Wpk = (const float*)d_in[8];  const float* bpk = (const float*)d_in[9];
    const float* relb = (const float*)d_in[10];
    const float* Wo  = (const float*)d_in[11]; const float* bo  = (const float*)d_in[12];

    float* out  = (float*)d_out;
    float* attn = out + (size_t)Mc * Dc;

    // ws (bf16 elems): Woh[0,1M) Wol[1M,2M) Wt[2M,6M) (ctxh overlays Wt)
    // Qc[6M,14M) Kc[14M,22M) VT[22M,26M)   -> 52 MB
    __bf16* ws   = (__bf16*)d_ws;
    __bf16* Woh  = ws;
    __bf16* Wol  = ws + (1u<<20);
    __bf16* Wt   = ws + (2u<<20);
    __bf16* ctxh = Wt;
    __bf16* Qc   = ws + (6u<<20);
    __bf16* Kc   = ws + (14u<<20);
    __bf16* VTb  = ws + (22u<<20);

    prep_kernel<<<dim3(16, 8, 5), 256, 0, stream>>>(Wcq, Wck, Wpq, Wpk, Wo, Wt, Woh, Wol);
    proj_kernel<<<dim3(1024), 256, 0, stream>>>(hidden, pos, Wt, bcq, bck, bpq, bpk, Qc, Kc);
    vt_kernel<<<dim3(Lc/128, 32), 256, 0, stream>>>(Kc, VTb);
    attn_kernel<<<dim3(512), 256, 0, stream>>>(Qc, Kc, VTb, relb, attn, ctxh);
    out_kernel<<<dim3(8, 32), 256, 0, stream>>>(ctxh, Woh, Wol, bo, out);
}

// Round 7
// 388.103 us; speedup vs baseline: 1.3947x; 1.3947x over previous
//
#include <hip/hip_runtime.h>
#include <hip/hip_bf16.h>
#include <math.h>

// RaffelAttention round 7.
// r6 + (a) sched_barrier fences pinning gl_lds/store issue order so counted
// vmcnt is exact (fixes the replay race), (b) software-pipelined passes:
// QK(kt+1) MFMAs overlap softmax/PV/store of tile kt.

#define Bc 2
#define Lc 2048
#define Dc 1024
#define Hc 16
#define Mc (Bc*Lc)
#define NT 32

typedef __attribute__((ext_vector_type(8))) __bf16 bf16x8;
typedef __attribute__((ext_vector_type(4))) float f32x4;
typedef __attribute__((ext_vector_type(16))) float f32x16;
typedef __attribute__((ext_vector_type(2))) unsigned u32x2;

union U4 { unsigned u[4]; bf16x8 v; };

__device__ __forceinline__ void gl_lds16(const void* g, void* l) {
    __builtin_amdgcn_global_load_lds(
        (const __attribute__((address_space(1))) void*)g,
        (__attribute__((address_space(3))) void*)l, 16, 0, 0);
}
__device__ __forceinline__ unsigned pkbf(float a, float b) {
    unsigned short ua = __builtin_bit_cast(unsigned short, (__bf16)a);
    unsigned short ub = __builtin_bit_cast(unsigned short, (__bf16)b);
    return (unsigned)ua | ((unsigned)ub << 16);
}
__device__ __forceinline__ float lo2f(unsigned u){ return __builtin_bit_cast(float, u << 16); }
__device__ __forceinline__ float hi2f(unsigned u){ return __builtin_bit_cast(float, u & 0xffff0000u); }

#define WAIT_VM0 asm volatile("s_waitcnt vmcnt(0)" ::: "memory")
#define WAIT_VM8 asm volatile("s_waitcnt vmcnt(8)" ::: "memory")
#define SBAR __builtin_amdgcn_sched_barrier(0)
#define BARRIER do { __builtin_amdgcn_sched_barrier(0); __builtin_amdgcn_s_barrier(); __builtin_amdgcn_sched_barrier(0); } while (0)

// ---------------------------------------------------------------------------
// prep: transpose weights to bf16 [n][k].  z=0..3 -> Wt[z]; z=4 -> Woh/Wol.
// ---------------------------------------------------------------------------
__global__ __launch_bounds__(256) void prep_kernel(
    const float* __restrict__ Wcq, const float* __restrict__ Wck,
    const float* __restrict__ Wpq, const float* __restrict__ Wpk,
    const float* __restrict__ Wo,
    __bf16* __restrict__ Wt, __bf16* __restrict__ Woh, __bf16* __restrict__ Wol)
{
    const int z = blockIdx.z;
    const float* W = (z==0)?Wcq:(z==1)?Wck:(z==2)?Wpq:(z==3)?Wpk:Wo;
    const int t = threadIdx.x;
    const int n  = blockIdx.x*64 + (t & 63);
    const int k0 = blockIdx.y*128 + (t >> 6)*32;
    float v[32];
    #pragma unroll
    for (int j = 0; j < 32; ++j) v[j] = W[(size_t)(k0+j)*Dc + n];
    if (z < 4) {
        __bf16* dst = Wt + (size_t)z*Dc*Dc + (size_t)n*Dc + k0;
        #pragma unroll
        for (int c = 0; c < 4; ++c) {
            bf16x8 o;
            #pragma unroll
            for (int j = 0; j < 8; ++j) o[j] = (__bf16)v[c*8+j];
            *(bf16x8*)(dst + c*8) = o;
        }
    } else {
        __bf16* dh = Woh + (size_t)n*Dc + k0;
        __bf16* dl = Wol + (size_t)n*Dc + k0;
        #pragma unroll
        for (int c = 0; c < 4; ++c) {
            bf16x8 oh, ol;
            #pragma unroll
            for (int j = 0; j < 8; ++j) {
                float x = v[c*8+j];
                __bf16 hi = (__bf16)x;
                oh[j] = hi; ol[j] = (__bf16)(x - (float)hi);
            }
            *(bf16x8*)(dh + c*8) = oh;
            *(bf16x8*)(dl + c*8) = ol;
        }
    }
}

// ---------------------------------------------------------------------------
// proj: X(fp32) @ Wt[z](bf16,[n][k]) -> Q'/K' bf16 [B,H,L,128] halves.
// ---------------------------------------------------------------------------
__global__ __launch_bounds__(256) void proj_kernel(
    const float* __restrict__ hidden, const float* __restrict__ pos,
    const __bf16* __restrict__ Wt,
    const float* __restrict__ bcq, const float* __restrict__ bck,
    const float* __restrict__ bpq, const float* __restrict__ bpk,
    __bf16* __restrict__ Qc, __bf16* __restrict__ Kc)
{
    const int g = blockIdx.x;
    const int nblk = g >> 7, sg = g & 127, mblk = sg & 31, z = sg >> 5;
    const int m0 = mblk*128, n0 = nblk*128;
    const float* X = (z < 2) ? hidden : pos;
    const __bf16* Wz = Wt + (size_t)z*Dc*Dc;
    const float* bias = (z==0)?bcq:(z==1)?bck:(z==2)?bpq:bpk;
    __bf16* dst = (z & 1) ? Kc : Qc;
    const int half = z >> 1;
    const float scale = (z & 1) ? 1.0f : 0.18033688011112042f; // 0.125*log2e on Q

    const int t = threadIdx.x, lane = t & 63, w = t >> 6;
    const int wm = w >> 1, wn = w & 1;

    __shared__ __align__(16) float  Asf[128][32];
    __shared__ __align__(16) __bf16 Bs[128][32];

    const int arowL = lane >> 3;
    const int acol  = ((lane & 7) ^ arowL) * 4;
    const int brow4 = lane >> 2;
    const int bcol  = ((lane & 3) ^ (brow4 & 3)) * 8;

    f32x4 acc[4][4] = {};

    for (int k0 = 0; k0 < Dc; k0 += 32) {
        #pragma unroll
        for (int i = 0; i < 4; ++i) {
            int row = 8*(4*w+i) + arowL;
            gl_lds16(X + (size_t)(m0+row)*Dc + k0 + acol, (char*)Asf + (4*w+i)*1024);
        }
        #pragma unroll
        for (int i = 0; i < 2; ++i) {
            int row = 16*(2*w+i) + brow4;
            gl_lds16(Wz + (size_t)(n0+row)*Dc + k0 + bcol, (char*)Bs + (2*w+i)*1024);
        }
        WAIT_VM0; __syncthreads();
        bf16x8 a[4], b[4];
        const int s2 = lane >> 4;
        #pragma unroll
        for (int i = 0; i < 4; ++i) {
            int R = wm*64 + i*16 + (lane&15);
            f32x4 x0 = *(const f32x4*)((const char*)&Asf[R][0] + (((2*s2  ) ^ (R&7))*16));
            f32x4 x1 = *(const f32x4*)((const char*)&Asf[R][0] + (((2*s2+1) ^ (R&7))*16));
            bf16x8 af;
            af[0]=(__bf16)x0[0]; af[1]=(__bf16)x0[1]; af[2]=(__bf16)x0[2]; af[3]=(__bf16)x0[3];
            af[4]=(__bf16)x1[0]; af[5]=(__bf16)x1[1]; af[6]=(__bf16)x1[2]; af[7]=(__bf16)x1[3];
            a[i] = af;
            int Rb = wn*64 + i*16 + (lane&15);
            b[i] = *(const bf16x8*)((const char*)&Bs[Rb][0] + ((s2 ^ (Rb&3))*16));
        }
        #pragma unroll
        for (int mi = 0; mi < 4; ++mi)
            #pragma unroll
            for (int ni = 0; ni < 4; ++ni)
                acc[mi][ni] = __builtin_amdgcn_mfma_f32_16x16x32_bf16(a[mi], b[ni], acc[mi][ni], 0, 0, 0);
        __syncthreads();
    }
    #pragma unroll
    for (int mi = 0; mi < 4; ++mi)
        #pragma unroll
        for (int ni = 0; ni < 4; ++ni)
            #pragma unroll
            for (int r = 0; r < 4; ++r) {
                int row = m0 + wm*64 + mi*16 + (lane>>4)*4 + r;
                int col = n0 + wn*64 + ni*16 + (lane&15);
                float v = (acc[mi][ni][r] + bias[col]) * scale;
                int bb = row >> 11, l = row & (Lc-1);
                int hh = col >> 6,  hd = col & 63;
                dst[(((size_t)bb*Hc + hh)*Lc + l)*128 + half*64 + hd] = (__bf16)v;
            }
}

// ---------------------------------------------------------------------------
// vt: VT[bh][d 0..63][l 0..2047] = Kc[bh][l][d]  (V = ck = first 64 dims)
// ---------------------------------------------------------------------------
__global__ __launch_bounds__(256) void vt_kernel(
    const __bf16* __restrict__ Kc, __bf16* __restrict__ VT)
{
    const int l0 = blockIdx.x * 128, hb = blockIdx.y;
    const int t = threadIdx.x, w = t >> 6, lane = t & 63;
    __shared__ __bf16 T[128][72];
    const __bf16* src = Kc + ((size_t)hb*Lc + l0)*128;
    {
        const int lr = t >> 3, cc = t & 7;
        #pragma unroll
        for (int j = 0; j < 4; ++j)
            *(bf16x8*)&T[lr + j*32][cc*8] = *(const bf16x8*)(src + (size_t)(lr + j*32)*128 + cc*8);
    }
    __syncthreads();
    {
        const int d = lane;
        __bf16* dstp = VT + ((size_t)hb*64 + d)*Lc + l0 + w*32;
        #pragma unroll
        for (int j = 0; j < 4; ++j) {
            bf16x8 o;
            #pragma unroll
            for (int i = 0; i < 8; ++i) o[i] = T[w*32 + j*8 + i][d];
            *(bf16x8*)(dstp + j*8) = o;
        }
    }
}

// ---------------------------------------------------------------------------
// attn: per (b,h,128-row q-tile). 4 waves, 32x32x16 MFMA, swapped QK^T.
// Pipelined: QK(kt+1) overlaps softmax/PV/store(kt). Fenced counted vmcnt.
// ---------------------------------------------------------------------------
__global__ __launch_bounds__(256, 2) void attn_kernel(
    const __bf16* __restrict__ Qc, const __bf16* __restrict__ Kc,
    const __bf16* __restrict__ VT, const float* __restrict__ rel_bias,
    float* __restrict__ attn, __bf16* __restrict__ ctxh)
{
    const int g = blockIdx.x;
    const int qt = g >> 5, hb = g & 31, h = hb & 15, bb = hb >> 4;
    const int q0 = qt * 128;
    const int t = threadIdx.x, lane = t & 63, w = t >> 6;
    const int ln31 = lane & 31, hi = lane >> 5;

    const __bf16* Qp = Qc + (size_t)hb * Lc * 128;
    const __bf16* Kp = Kc + (size_t)hb * Lc * 128;
    const __bf16* Vp = VT + (size_t)hb * 64 * Lc;

    // LDS: Ks dbuf 32KB | Vs dbuf 16KB | Ps per-wave 16KB  = 64KB
    __shared__ __align__(16) char smem[65536];
    char* const VsB = smem + 32768;
    char* const PsW = smem + 49152 + w*4096;

    // Q fragments (B operand): col = q = w*32+ln31, k = ks*16 + hi*8
    bf16x8 qa[8];
    {
        const __bf16* qrow = Qp + (size_t)(q0 + w*32 + ln31) * 128 + hi*8;
        #pragma unroll
        for (int ks = 0; ks < 8; ++ks) qa[ks] = *(const bf16x8*)(qrow + ks*16);
    }

    // staging source offsets (inverse-swizzled; LDS dest linear)
    int kof[4];
    #pragma unroll
    for (int c = 0; c < 4; ++c) {
        int rl = c*4 + (lane >> 4);
        int rr = w*16 + rl;
        kof[c] = rr*128 + (((lane & 15) ^ rl) * 8);
    }
    int vof[2];
    #pragma unroll
    for (int c = 0; c < 2; ++c) {
        int dl = lane >> 3;
        int dd = w*16 + c*8 + dl;
        vof[c] = dd*2048 + (((lane & 7) ^ dl) * 8);
    }
    int kR[8];
    #pragma unroll
    for (int ks = 0; ks < 8; ++ks) kR[ks] = ((ks*2 + hi) ^ (lane & 15)) * 8;
    int vR[4];
    #pragma unroll
    for (int ks = 0; ks < 4; ++ks) vR[ks] = ((ks*2 + hi) ^ (lane & 7)) * 8;

    #define STAGE_K(B, KT) do { \
        const __bf16* kb_ = Kp + (size_t)(KT)*8192; \
        gl_lds16(kb_ + kof[0], smem + ((B)*64 + w*16 +  0)*256); \
        gl_lds16(kb_ + kof[1], smem + ((B)*64 + w*16 +  4)*256); \
        gl_lds16(kb_ + kof[2], smem + ((B)*64 + w*16 +  8)*256); \
        gl_lds16(kb_ + kof[3], smem + ((B)*64 + w*16 + 12)*256); \
    } while (0)
    #define STAGE_V(B, KT) do { \
        const __bf16* vb_ = Vp + (KT)*64; \
        gl_lds16(vb_ + vof[0], VsB + ((B)*64 + w*16 + 0)*128); \
        gl_lds16(vb_ + vof[1], VsB + ((B)*64 + w*16 + 8)*128); \
    } while (0)
    #define KB(B, ROW, KS) (*(const bf16x8*)(smem + ((B)*64 + (ROW))*256 + kR[KS]*2))
    #define VB(B, ROW, KS) (*(const bf16x8*)(VsB  + ((B)*64 + (ROW))*128 + vR[KS]*2))

    #define QK_CLUSTER(B, S0, S1) do { \
        __builtin_amdgcn_s_setprio(1); \
        _Pragma("unroll") \
        for (int ks = 0; ks < 8; ++ks) { \
            bf16x8 kb0 = KB(B, ln31, ks); \
            bf16x8 kb1 = KB(B, 32 + ln31, ks); \
            S0 = __builtin_amdgcn_mfma_f32_32x32x16_bf16(kb0, qa[ks], S0, 0, 0, 0); \
            S1 = __builtin_amdgcn_mfma_f32_32x32x16_bf16(kb1, qa[ks], S1, 0, 0, 0); \
        } \
        __builtin_amdgcn_s_setprio(0); \
    } while (0)

    const float bc = rel_bias[h] * 0.18033688011112042f;

    // ---------------- pass 1: per-lane scalar sumexp, pipelined
    float lsum = 0.f;
    f32x16 s0 = {}, s1 = {};
    STAGE_K(0, 0);
    WAIT_VM0; BARRIER;
    QK_CLUSTER(0, s0, s1);
    STAGE_K(1, 1);
    WAIT_VM0; BARRIER;                       // K1 ready; all waves done with Ks0
    for (int kt = 0; kt < NT-1; ++kt) {
        if (kt+2 < NT) STAGE_K(kt & 1, kt+2);
        SBAR;                                 // pin gl_lds before compute
        const int cb = (kt+1) & 1;
        f32x16 sn0 = {}, sn1 = {};
        QK_CLUSTER(cb, sn0, sn1);
        #pragma unroll
        for (int r = 0; r < 16; ++r)
            lsum += exp2f(s0[r] + bc) + exp2f(s1[r] + bc);
        WAIT_VM0; BARRIER;
        s0 = sn0; s1 = sn1;
    }
    #pragma unroll
    for (int r = 0; r < 16; ++r)
        lsum += exp2f(s0[r] + bc) + exp2f(s1[r] + bc);
    lsum += __shfl_xor(lsum, 32);
    const float badd = bc - log2f(lsum);

    // ---------------- pass 2: P out + PV, pipelined
    f32x16 ctx0 = {}, ctx1 = {};
    float* abase = attn + ((size_t)hb*Lc + q0 + w*32)*Lc;
    const int rr2 = lane >> 4;
    const int s8  = lane & 15;

    #define SOFTPV(KT) do { \
        unsigned u0[8], u1[8], r0[8], r1[8]; \
        _Pragma("unroll") \
        for (int gq = 0; gq < 4; ++gq) { \
            u0[gq]   = pkbf(exp2f(s0[4*gq+0]+badd), exp2f(s0[4*gq+1]+badd)); \
            u1[gq]   = pkbf(exp2f(s0[4*gq+2]+badd), exp2f(s0[4*gq+3]+badd)); \
            u0[4+gq] = pkbf(exp2f(s1[4*gq+0]+badd), exp2f(s1[4*gq+1]+badd)); \
            u1[4+gq] = pkbf(exp2f(s1[4*gq+2]+badd), exp2f(s1[4*gq+3]+badd)); \
        } \
        _Pragma("unroll") \
        for (int gq = 0; gq < 8; ++gq) { \
            r0[gq] = __shfl_xor(u0[gq], 32); \
            r1[gq] = __shfl_xor(u1[gq], 32); \
        } \
        bf16x8 pb[4]; \
        _Pragma("unroll") \
        for (int ks = 0; ks < 4; ++ks) { \
            const int gq = 2*ks + hi; \
            U4 u; \
            u.u[0] = hi ? r0[gq] : u0[gq]; \
            u.u[1] = hi ? r1[gq] : u1[gq]; \
            u.u[2] = hi ? u0[gq] : r0[gq]; \
            u.u[3] = hi ? u1[gq] : r1[gq]; \
            pb[ks] = u.v; \
            *(bf16x8*)(PsW + ln31*128 + ((gq ^ (ln31 & 7))*16)) = u.v; \
        } \
        __builtin_amdgcn_s_setprio(1); \
        _Pragma("unroll") \
        for (int ks = 0; ks < 4; ++ks) { \
            bf16x8 v0 = VB((KT) & 1, ln31, ks); \
            bf16x8 v1 = VB((KT) & 1, 32 + ln31, ks); \
            ctx0 = __builtin_amdgcn_mfma_f32_32x32x16_bf16(pb[ks], v0, ctx0, 0, 0, 0); \
            ctx1 = __builtin_amdgcn_mfma_f32_32x32x16_bf16(pb[ks], v1, ctx1, 0, 0, 0); \
        } \
        __builtin_amdgcn_s_setprio(0); \
        SBAR;  /* pin stores after gl_lds + compute */ \
        _Pragma("unroll") \
        for (int j = 0; j < 8; ++j) { \
            const int row = j*4 + rr2; \
            u32x2 d = *(const u32x2*)(PsW + row*128 + (((s8>>1) ^ (row&7))*16) + (s8&1)*8); \
            f32x4 o; \
            o[0]=lo2f(d[0]); o[1]=hi2f(d[0]); o[2]=lo2f(d[1]); o[3]=hi2f(d[1]); \
            *(f32x4*)(abase + (size_t)row*Lc + (KT)*64 + s8*4) = o; \
        } \
    } while (0)

    {   // prologue: K0 -> Ks0, S(t0); then K1 -> Ks1, V0 -> Vs0
        f32x16 zz = {};
        s0 = zz; s1 = zz;
        STAGE_K(0, 0);
        WAIT_VM0; BARRIER;
        QK_CLUSTER(0, s0, s1);
        STAGE_K(1, 1); STAGE_V(0, 0);
        WAIT_VM0; BARRIER;                   // K1,V0 ready; waves done with Ks0
    }
    for (int kt = 0; kt < NT-1; ++kt) {
        if (kt+2 < NT) STAGE_K(kt & 1, kt+2);
        STAGE_V((kt+1) & 1, kt+1);
        SBAR;                                 // pin gl_lds before compute
        const int cb = (kt+1) & 1;
        f32x16 sn0 = {}, sn1 = {};
        QK_CLUSTER(cb, sn0, sn1);             // independent of SOFTPV(kt) below
        SOFTPV(kt);
        WAIT_VM8; BARRIER;                    // this iter's gl_lds done; 8 stores fly
        s0 = sn0; s1 = sn1;
    }
    SOFTPV(NT-1);

    #pragma unroll
    for (int r = 0; r < 16; ++r) {
        const int R = (r&3) + 8*(r>>2) + 4*hi;
        const size_t row = (size_t)bb*Lc + q0 + w*32 + R;
        ctxh[row*Dc + h*64 + ln31]      = (__bf16)ctx0[r];
        ctxh[row*Dc + h*64 + 32 + ln31] = (__bf16)ctx1[r];
    }
    #undef SOFTPV
    #undef QK_CLUSTER
    #undef STAGE_K
    #undef STAGE_V
    #undef KB
    #undef VB
}

// ---------------------------------------------------------------------------
// out: ctxh(bf16) @ Wo + bo, B split hi/lo.  m97-style gload_lds + swizzle.
// ---------------------------------------------------------------------------
__global__ __launch_bounds__(256) void out_kernel(
    const __bf16* __restrict__ ctxh, const __bf16* __restrict__ Woh,
    const __bf16* __restrict__ Wol, const float* __restrict__ bo,
    float* __restrict__ out)
{
    const int m0 = blockIdx.y * 128, n0 = blockIdx.x * 128;
    const int t = threadIdx.x, lane = t & 63, w = t >> 6;
    const int wm = w >> 1, wn = w & 1;

    __shared__ __align__(16) __bf16 As[128][32];
    __shared__ __align__(16) __bf16 Bh[128][32];
    __shared__ __align__(16) __bf16 Bl[128][32];

    const int row4 = lane >> 2;
    const int scol = ((lane & 3) ^ (row4 & 3)) * 8;

    f32x4 acc[4][4] = {};

    for (int k0 = 0; k0 < Dc; k0 += 32) {
        #pragma unroll
        for (int i = 0; i < 2; ++i) {
            int row = 16*(2*w+i) + row4;
            gl_lds16(ctxh + (size_t)(m0+row)*Dc + k0 + scol, (char*)As + (2*w+i)*1024);
            gl_lds16(Woh  + (size_t)(n0+row)*Dc + k0 + scol, (char*)Bh + (2*w+i)*1024);
            gl_lds16(Wol  + (size_t)(n0+row)*Dc + k0 + scol, (char*)Bl + (2*w+i)*1024);
        }
        WAIT_VM0; __syncthreads();
        bf16x8 a[4], bh[4], bl[4];
        const int s2 = lane >> 4;
        #pragma unroll
        for (int i = 0; i < 4; ++i) {
            int Ra = wm*64 + i*16 + (lane&15);
            int Rb = wn*64 + i*16 + (lane&15);
            a[i]  = *(const bf16x8*)((const char*)&As[Ra][0] + ((s2 ^ (Ra&3))*16));
            bh[i] = *(const bf16x8*)((const char*)&Bh[Rb][0] + ((s2 ^ (Rb&3))*16));
            bl[i] = *(const bf16x8*)((const char*)&Bl[Rb][0] + ((s2 ^ (Rb&3))*16));
        }
        #pragma unroll
        for (int mi = 0; mi < 4; ++mi)
            #pragma unroll
            for (int ni = 0; ni < 4; ++ni) {
                acc[mi][ni] = __builtin_amdgcn_mfma_f32_16x16x32_bf16(a[mi], bh[ni], acc[mi][ni], 0, 0, 0);
                acc[mi][ni] = __builtin_amdgcn_mfma_f32_16x16x32_bf16(a[mi], bl[ni], acc[mi][ni], 0, 0, 0);
            }
        __syncthreads();
    }
    #pragma unroll
    for (int mi = 0; mi < 4; ++mi)
        #pragma unroll
        for (int ni = 0; ni < 4; ++ni)
            #pragma unroll
            for (int r = 0; r < 4; ++r) {
                int row = m0 + wm*64 + mi*16 + (lane>>4)*4 + r;
                int col = n0 + wn*64 + ni*16 + (lane&15);
                out[(size_t)row * Dc + col] = acc[mi][ni][r] + bo[col];
            }
}

// ---------------------------------------------------------------------------
extern "C" void kernel_launch(void* const* d_in, const int* in_sizes, int n_in,
                              void* d_out, int out_size, void* d_ws, size_t ws_size,
                              hipStream_t stream)
{
    const float* hidden = (const float*)d_in[0];
    const float* pos    = (const float*)d_in[1];
    const float* Wcq = (const float*)d_in[2];  const float* bcq = (const float*)d_in[3];
    const float* Wck = (const float*)d_in[4];  const float* bck = (const float*)d_in[5];
    const float* Wpq = (const float*)d_in[6];  const float* bpq = (const float*)d_in[7];
    const float* Wpk = (const float*)d_in[8];  const float* bpk = (const float*)d_in[9];
    const float* relb = (const float*)d_in[10];
    const float* Wo  = (const float*)d_in[11]; const float* bo  = (const float*)d_in[12];

    float* out  = (float*)d_out;
    float* attn = out + (size_t)Mc * Dc;

    // ws (bf16 elems): Woh[0,1M) Wol[1M,2M) Wt[2M,6M) (ctxh overlays Wt)
    // Qc[6M,14M) Kc[14M,22M) VT[22M,26M)   -> 52 MB
    __bf16* ws   = (__bf16*)d_ws;
    __bf16* Woh  = ws;
    __bf16* Wol  = ws + (1u<<20);
    __bf16* Wt   = ws + (2u<<20);
    __bf16* ctxh = Wt;
    __bf16* Qc   = ws + (6u<<20);
    __bf16* Kc   = ws + (14u<<20);
    __bf16* VTb  = ws + (22u<<20);

    prep_kernel<<<dim3(16, 8, 5), 256, 0, stream>>>(Wcq, Wck, Wpq, Wpk, Wo, Wt, Woh, Wol);
    proj_kernel<<<dim3(1024), 256, 0, stream>>>(hidden, pos, Wt, bcq, bck, bpq, bpk, Qc, Kc);
    vt_kernel<<<dim3(Lc/128, 32), 256, 0, stream>>>(Kc, VTb);
    attn_kernel<<<dim3(512), 256, 0, stream>>>(Qc, Kc, VTb, relb, attn, ctxh);
    out_kernel<<<dim3(8, 32), 256, 0, stream>>>(ctxh, Woh, Wol, bo, out);
}

// Round 8
// 385.428 us; speedup vs baseline: 1.4044x; 1.0069x over previous
//
#include <hip/hip_runtime.h>
#include <hip/hip_bf16.h>
#include <math.h>

// RaffelAttention round 8.
// attn split into attn1 (lsum -> badd scratch; 3-buf K, counted vmcnt(4)) and
// attn2 (P + PV; K 3-buf / V 2-buf, counted vmcnt(12), wave-local Ps, one
// barrier per iter). Prefetch never drains in steady state.

#define Bc 2
#define Lc 2048
#define Dc 1024
#define Hc 16
#define Mc (Bc*Lc)
#define NT 32

typedef __attribute__((ext_vector_type(8))) __bf16 bf16x8;
typedef __attribute__((ext_vector_type(4))) float f32x4;
typedef __attribute__((ext_vector_type(16))) float f32x16;
typedef __attribute__((ext_vector_type(2))) unsigned u32x2;

union U4 { unsigned u[4]; bf16x8 v; };

__device__ __forceinline__ void gl_lds16(const void* g, void* l) {
    __builtin_amdgcn_global_load_lds(
        (const __attribute__((address_space(1))) void*)g,
        (__attribute__((address_space(3))) void*)l, 16, 0, 0);
}
__device__ __forceinline__ unsigned pkbf(float a, float b) {
    unsigned short ua = __builtin_bit_cast(unsigned short, (__bf16)a);
    unsigned short ub = __builtin_bit_cast(unsigned short, (__bf16)b);
    return (unsigned)ua | ((unsigned)ub << 16);
}
__device__ __forceinline__ float lo2f(unsigned u){ return __builtin_bit_cast(float, u << 16); }
__device__ __forceinline__ float hi2f(unsigned u){ return __builtin_bit_cast(float, u & 0xffff0000u); }

#define WAIT_VM0  asm volatile("s_waitcnt vmcnt(0)" ::: "memory")
#define WAIT_VM4  asm volatile("s_waitcnt vmcnt(4)" ::: "memory")
#define WAIT_VM8  asm volatile("s_waitcnt vmcnt(8)" ::: "memory")
#define WAIT_VM12 asm volatile("s_waitcnt vmcnt(12)" ::: "memory")
#define WAIT_LG0  asm volatile("s_waitcnt lgkmcnt(0)" ::: "memory")
#define SBAR __builtin_amdgcn_sched_barrier(0)
#define BARRIER do { __builtin_amdgcn_sched_barrier(0); __builtin_amdgcn_s_barrier(); __builtin_amdgcn_sched_barrier(0); } while (0)

// ---------------------------------------------------------------------------
// prep: transpose weights to bf16 [n][k].  z=0..3 -> Wt[z]; z=4 -> Woh/Wol.
// ---------------------------------------------------------------------------
__global__ __launch_bounds__(256) void prep_kernel(
    const float* __restrict__ Wcq, const float* __restrict__ Wck,
    const float* __restrict__ Wpq, const float* __restrict__ Wpk,
    const float* __restrict__ Wo,
    __bf16* __restrict__ Wt, __bf16* __restrict__ Woh, __bf16* __restrict__ Wol)
{
    const int z = blockIdx.z;
    const float* W = (z==0)?Wcq:(z==1)?Wck:(z==2)?Wpq:(z==3)?Wpk:Wo;
    const int t = threadIdx.x;
    const int n  = blockIdx.x*64 + (t & 63);
    const int k0 = blockIdx.y*128 + (t >> 6)*32;
    float v[32];
    #pragma unroll
    for (int j = 0; j < 32; ++j) v[j] = W[(size_t)(k0+j)*Dc + n];
    if (z < 4) {
        __bf16* dst = Wt + (size_t)z*Dc*Dc + (size_t)n*Dc + k0;
        #pragma unroll
        for (int c = 0; c < 4; ++c) {
            bf16x8 o;
            #pragma unroll
            for (int j = 0; j < 8; ++j) o[j] = (__bf16)v[c*8+j];
            *(bf16x8*)(dst + c*8) = o;
        }
    } else {
        __bf16* dh = Woh + (size_t)n*Dc + k0;
        __bf16* dl = Wol + (size_t)n*Dc + k0;
        #pragma unroll
        for (int c = 0; c < 4; ++c) {
            bf16x8 oh, ol;
            #pragma unroll
            for (int j = 0; j < 8; ++j) {
                float x = v[c*8+j];
                __bf16 hi = (__bf16)x;
                oh[j] = hi; ol[j] = (__bf16)(x - (float)hi);
            }
            *(bf16x8*)(dh + c*8) = oh;
            *(bf16x8*)(dl + c*8) = ol;
        }
    }
}

// ---------------------------------------------------------------------------
// proj: X(fp32) @ Wt[z](bf16,[n][k]) -> Q'/K' bf16 [B,H,L,128] halves.
// ---------------------------------------------------------------------------
__global__ __launch_bounds__(256) void proj_kernel(
    const float* __restrict__ hidden, const float* __restrict__ pos,
    const __bf16* __restrict__ Wt,
    const float* __restrict__ bcq, const float* __restrict__ bck,
    const float* __restrict__ bpq, const float* __restrict__ bpk,
    __bf16* __restrict__ Qc, __bf16* __restrict__ Kc)
{
    const int g = blockIdx.x;
    const int nblk = g >> 7, sg = g & 127, mblk = sg & 31, z = sg >> 5;
    const int m0 = mblk*128, n0 = nblk*128;
    const float* X = (z < 2) ? hidden : pos;
    const __bf16* Wz = Wt + (size_t)z*Dc*Dc;
    const float* bias = (z==0)?bcq:(z==1)?bck:(z==2)?bpq:bpk;
    __bf16* dst = (z & 1) ? Kc : Qc;
    const int half = z >> 1;
    const float scale = (z & 1) ? 1.0f : 0.18033688011112042f; // 0.125*log2e on Q

    const int t = threadIdx.x, lane = t & 63, w = t >> 6;
    const int wm = w >> 1, wn = w & 1;

    __shared__ __align__(16) float  Asf[128][32];
    __shared__ __align__(16) __bf16 Bs[128][32];

    const int arowL = lane >> 3;
    const int acol  = ((lane & 7) ^ arowL) * 4;
    const int brow4 = lane >> 2;
    const int bcol  = ((lane & 3) ^ (brow4 & 3)) * 8;

    f32x4 acc[4][4] = {};

    for (int k0 = 0; k0 < Dc; k0 += 32) {
        #pragma unroll
        for (int i = 0; i < 4; ++i) {
            int row = 8*(4*w+i) + arowL;
            gl_lds16(X + (size_t)(m0+row)*Dc + k0 + acol, (char*)Asf + (4*w+i)*1024);
        }
        #pragma unroll
        for (int i = 0; i < 2; ++i) {
            int row = 16*(2*w+i) + brow4;
            gl_lds16(Wz + (size_t)(n0+row)*Dc + k0 + bcol, (char*)Bs + (2*w+i)*1024);
        }
        WAIT_VM0; __syncthreads();
        bf16x8 a[4], b[4];
        const int s2 = lane >> 4;
        #pragma unroll
        for (int i = 0; i < 4; ++i) {
            int R = wm*64 + i*16 + (lane&15);
            f32x4 x0 = *(const f32x4*)((const char*)&Asf[R][0] + (((2*s2  ) ^ (R&7))*16));
            f32x4 x1 = *(const f32x4*)((const char*)&Asf[R][0] + (((2*s2+1) ^ (R&7))*16));
            bf16x8 af;
            af[0]=(__bf16)x0[0]; af[1]=(__bf16)x0[1]; af[2]=(__bf16)x0[2]; af[3]=(__bf16)x0[3];
            af[4]=(__bf16)x1[0]; af[5]=(__bf16)x1[1]; af[6]=(__bf16)x1[2]; af[7]=(__bf16)x1[3];
            a[i] = af;
            int Rb = wn*64 + i*16 + (lane&15);
            b[i] = *(const bf16x8*)((const char*)&Bs[Rb][0] + ((s2 ^ (Rb&3))*16));
        }
        #pragma unroll
        for (int mi = 0; mi < 4; ++mi)
            #pragma unroll
            for (int ni = 0; ni < 4; ++ni)
                acc[mi][ni] = __builtin_amdgcn_mfma_f32_16x16x32_bf16(a[mi], b[ni], acc[mi][ni], 0, 0, 0);
        __syncthreads();
    }
    #pragma unroll
    for (int mi = 0; mi < 4; ++mi)
        #pragma unroll
        for (int ni = 0; ni < 4; ++ni)
            #pragma unroll
            for (int r = 0; r < 4; ++r) {
                int row = m0 + wm*64 + mi*16 + (lane>>4)*4 + r;
                int col = n0 + wn*64 + ni*16 + (lane&15);
                float v = (acc[mi][ni][r] + bias[col]) * scale;
                int bb = row >> 11, l = row & (Lc-1);
                int hh = col >> 6,  hd = col & 63;
                dst[(((size_t)bb*Hc + hh)*Lc + l)*128 + half*64 + hd] = (__bf16)v;
            }
}

// ---------------------------------------------------------------------------
// vt: VT[bh][d 0..63][l 0..2047] = Kc[bh][l][d]  (V = ck = first 64 dims)
// ---------------------------------------------------------------------------
__global__ __launch_bounds__(256) void vt_kernel(
    const __bf16* __restrict__ Kc, __bf16* __restrict__ VT)
{
    const int l0 = blockIdx.x * 128, hb = blockIdx.y;
    const int t = threadIdx.x, w = t >> 6, lane = t & 63;
    __shared__ __bf16 T[128][72];
    const __bf16* src = Kc + ((size_t)hb*Lc + l0)*128;
    {
        const int lr = t >> 3, cc = t & 7;
        #pragma unroll
        for (int j = 0; j < 4; ++j)
            *(bf16x8*)&T[lr + j*32][cc*8] = *(const bf16x8*)(src + (size_t)(lr + j*32)*128 + cc*8);
    }
    __syncthreads();
    {
        const int d = lane;
        __bf16* dstp = VT + ((size_t)hb*64 + d)*Lc + l0 + w*32;
        #pragma unroll
        for (int j = 0; j < 4; ++j) {
            bf16x8 o;
            #pragma unroll
            for (int i = 0; i < 8; ++i) o[i] = T[w*32 + j*8 + i][d];
            *(bf16x8*)(dstp + j*8) = o;
        }
    }
}

// ---------------------------------------------------------------------------
// attn1: lsum pass. per (b,h,128-q-tile); 3-buf K, counted vmcnt(4).
// writes badd[hb][q] = bc - log2(lsum).
// ---------------------------------------------------------------------------
__global__ __launch_bounds__(256, 2) void attn1_kernel(
    const __bf16* __restrict__ Qc, const __bf16* __restrict__ Kc,
    const float* __restrict__ rel_bias, float* __restrict__ baddp)
{
    const int g = blockIdx.x;
    const int qt = g >> 5, hb = g & 31, h = hb & 15;
    const int q0 = qt * 128;
    const int t = threadIdx.x, lane = t & 63, w = t >> 6;
    const int ln31 = lane & 31, hi = lane >> 5;

    const __bf16* Qp = Qc + (size_t)hb * Lc * 128;
    const __bf16* Kp = Kc + (size_t)hb * Lc * 128;

    __shared__ __align__(16) char smem[49152];   // 3 x 16KB K buffers

    bf16x8 qa[8];
    {
        const __bf16* qrow = Qp + (size_t)(q0 + w*32 + ln31) * 128 + hi*8;
        #pragma unroll
        for (int ks = 0; ks < 8; ++ks) qa[ks] = *(const bf16x8*)(qrow + ks*16);
    }

    int kof[4];
    #pragma unroll
    for (int c = 0; c < 4; ++c) {
        int rl = c*4 + (lane >> 4);
        int rr = w*16 + rl;
        kof[c] = rr*128 + (((lane & 15) ^ rl) * 8);
    }
    int kR[8];
    #pragma unroll
    for (int ks = 0; ks < 8; ++ks) kR[ks] = ((ks*2 + hi) ^ (lane & 15)) * 8;

    #define STAGE_K(B, KT) do { \
        const __bf16* kb_ = Kp + (size_t)(KT)*8192; \
        gl_lds16(kb_ + kof[0], smem + ((B)*64 + w*16 +  0)*256); \
        gl_lds16(kb_ + kof[1], smem + ((B)*64 + w*16 +  4)*256); \
        gl_lds16(kb_ + kof[2], smem + ((B)*64 + w*16 +  8)*256); \
        gl_lds16(kb_ + kof[3], smem + ((B)*64 + w*16 + 12)*256); \
    } while (0)
    #define KB(B, ROW, KS) (*(const bf16x8*)(smem + ((B)*64 + (ROW))*256 + kR[KS]*2))

    const float bc = rel_bias[h] * 0.18033688011112042f;
    float lsum = 0.f;

    STAGE_K(0, 0); STAGE_K(1, 1);
    WAIT_VM4; BARRIER;                       // K0 ready; K1 in flight
    for (int kt = 0; kt < NT; ++kt) {
        if (kt+2 < NT) STAGE_K((kt+2) % 3, kt+2);
        SBAR;
        const int buf = kt % 3;
        f32x16 s0 = {}, s1 = {};
        __builtin_amdgcn_s_setprio(1);
        #pragma unroll
        for (int ks = 0; ks < 8; ++ks) {
            bf16x8 kb0 = KB(buf, ln31, ks);
            bf16x8 kb1 = KB(buf, 32 + ln31, ks);
            s0 = __builtin_amdgcn_mfma_f32_32x32x16_bf16(kb0, qa[ks], s0, 0, 0, 0);
            s1 = __builtin_amdgcn_mfma_f32_32x32x16_bf16(kb1, qa[ks], s1, 0, 0, 0);
        }
        __builtin_amdgcn_s_setprio(0);
        #pragma unroll
        for (int r = 0; r < 16; ++r)
            lsum += exp2f(s0[r] + bc) + exp2f(s1[r] + bc);
        if (kt+2 < NT) { WAIT_VM4; } else { WAIT_VM0; }
        BARRIER;
    }
    lsum += __shfl_xor(lsum, 32);
    if (!hi) baddp[(size_t)hb*Lc + q0 + w*32 + ln31] = bc - log2f(lsum);
    #undef STAGE_K
    #undef KB
}

// ---------------------------------------------------------------------------
// attn2: P out + PV. K 3-buf / V 2-buf / wave-local Ps. Counted vmcnt(12):
// prefetch (K kt+2) and this iter's 8 P-stores stay in flight across barrier.
// ---------------------------------------------------------------------------
__global__ __launch_bounds__(256, 2) void attn2_kernel(
    const __bf16* __restrict__ Qc, const __bf16* __restrict__ Kc,
    const __bf16* __restrict__ VT, const float* __restrict__ baddp,
    float* __restrict__ attn, __bf16* __restrict__ ctxh)
{
    const int g = blockIdx.x;
    const int qt = g >> 5, hb = g & 31, h = hb & 15, bb = hb >> 4;
    const int q0 = qt * 128;
    const int t = threadIdx.x, lane = t & 63, w = t >> 6;
    const int ln31 = lane & 31, hi = lane >> 5;

    const __bf16* Qp = Qc + (size_t)hb * Lc * 128;
    const __bf16* Kp = Kc + (size_t)hb * Lc * 128;
    const __bf16* Vp = VT + (size_t)hb * 64 * Lc;

    // LDS: K 3x16KB @0 | V 2x8KB @49152 | Ps 4x4KB @65536   = 80KB
    __shared__ __align__(16) char smem[81920];
    char* const VsB = smem + 49152;
    char* const PsW = smem + 65536 + w*4096;

    bf16x8 qa[8];
    {
        const __bf16* qrow = Qp + (size_t)(q0 + w*32 + ln31) * 128 + hi*8;
        #pragma unroll
        for (int ks = 0; ks < 8; ++ks) qa[ks] = *(const bf16x8*)(qrow + ks*16);
    }
    const float badd = baddp[(size_t)hb*Lc + q0 + w*32 + ln31];

    int kof[4];
    #pragma unroll
    for (int c = 0; c < 4; ++c) {
        int rl = c*4 + (lane >> 4);
        int rr = w*16 + rl;
        kof[c] = rr*128 + (((lane & 15) ^ rl) * 8);
    }
    int vof[2];
    #pragma unroll
    for (int c = 0; c < 2; ++c) {
        int dl = lane >> 3;
        int dd = w*16 + c*8 + dl;
        vof[c] = dd*2048 + (((lane & 7) ^ dl) * 8);
    }
    int kR[8];
    #pragma unroll
    for (int ks = 0; ks < 8; ++ks) kR[ks] = ((ks*2 + hi) ^ (lane & 15)) * 8;
    int vR[4];
    #pragma unroll
    for (int ks = 0; ks < 4; ++ks) vR[ks] = ((ks*2 + hi) ^ (lane & 7)) * 8;

    #define STAGE_K(B, KT) do { \
        const __bf16* kb_ = Kp + (size_t)(KT)*8192; \
        gl_lds16(kb_ + kof[0], smem + ((B)*64 + w*16 +  0)*256); \
        gl_lds16(kb_ + kof[1], smem + ((B)*64 + w*16 +  4)*256); \
        gl_lds16(kb_ + kof[2], smem + ((B)*64 + w*16 +  8)*256); \
        gl_lds16(kb_ + kof[3], smem + ((B)*64 + w*16 + 12)*256); \
    } while (0)
    #define STAGE_V(B, KT) do { \
        const __bf16* vb_ = Vp + (KT)*64; \
        gl_lds16(vb_ + vof[0], VsB + ((B)*64 + w*16 + 0)*128); \
        gl_lds16(vb_ + vof[1], VsB + ((B)*64 + w*16 + 8)*128); \
    } while (0)
    #define KB(B, ROW, KS) (*(const bf16x8*)(smem + ((B)*64 + (ROW))*256 + kR[KS]*2))
    #define VB(B, ROW, KS) (*(const bf16x8*)(VsB  + ((B)*64 + (ROW))*128 + vR[KS]*2))

    f32x16 ctx0 = {}, ctx1 = {};
    float* abase = attn + ((size_t)hb*Lc + q0 + w*32)*Lc;
    const int rr2 = lane >> 4;
    const int s8  = lane & 15;

    // prologue: K0, V0 needed; K1 in flight
    STAGE_K(0, 0); STAGE_V(0, 0); STAGE_K(1, 1);
    WAIT_VM4; BARRIER;

    for (int kt = 0; kt < NT; ++kt) {
        if (kt+1 < NT) STAGE_V((kt+1) & 1, kt+1);     // V first (drained by vm12)
        if (kt+2 < NT) STAGE_K((kt+2) % 3, kt+2);     // K second (stays in flight)
        SBAR;
        const int buf = kt % 3;
        f32x16 s0 = {}, s1 = {};
        __builtin_amdgcn_s_setprio(1);
        #pragma unroll
        for (int ks = 0; ks < 8; ++ks) {
            bf16x8 kb0 = KB(buf, ln31, ks);
            bf16x8 kb1 = KB(buf, 32 + ln31, ks);
            s0 = __builtin_amdgcn_mfma_f32_32x32x16_bf16(kb0, qa[ks], s0, 0, 0, 0);
            s1 = __builtin_amdgcn_mfma_f32_32x32x16_bf16(kb1, qa[ks], s1, 0, 0, 0);
        }
        __builtin_amdgcn_s_setprio(0);
        // p = exp2(s + badd); pack pairs; exchange hi/lo kv halves
        unsigned u0[8], u1[8], r0[8], r1[8];
        #pragma unroll
        for (int gq = 0; gq < 4; ++gq) {
            u0[gq]   = pkbf(exp2f(s0[4*gq+0]+badd), exp2f(s0[4*gq+1]+badd));
            u1[gq]   = pkbf(exp2f(s0[4*gq+2]+badd), exp2f(s0[4*gq+3]+badd));
            u0[4+gq] = pkbf(exp2f(s1[4*gq+0]+badd), exp2f(s1[4*gq+1]+badd));
            u1[4+gq] = pkbf(exp2f(s1[4*gq+2]+badd), exp2f(s1[4*gq+3]+badd));
        }
        #pragma unroll
        for (int gq = 0; gq < 8; ++gq) {
            r0[gq] = __shfl_xor(u0[gq], 32);
            r1[gq] = __shfl_xor(u1[gq], 32);
        }
        bf16x8 pb[4];
        #pragma unroll
        for (int ks = 0; ks < 4; ++ks) {
            const int gq = 2*ks + hi;
            U4 u;
            u.u[0] = hi ? r0[gq] : u0[gq];
            u.u[1] = hi ? r1[gq] : u1[gq];
            u.u[2] = hi ? u0[gq] : r0[gq];
            u.u[3] = hi ? u1[gq] : r1[gq];
            pb[ks] = u.v;
            *(bf16x8*)(PsW + ln31*128 + ((gq ^ (ln31 & 7))*16)) = u.v;
        }
        __builtin_amdgcn_s_setprio(1);
        #pragma unroll
        for (int ks = 0; ks < 4; ++ks) {
            bf16x8 v0 = VB(kt & 1, ln31, ks);
            bf16x8 v1 = VB(kt & 1, 32 + ln31, ks);
            ctx0 = __builtin_amdgcn_mfma_f32_32x32x16_bf16(pb[ks], v0, ctx0, 0, 0, 0);
            ctx1 = __builtin_amdgcn_mfma_f32_32x32x16_bf16(pb[ks], v1, ctx1, 0, 0, 0);
        }
        __builtin_amdgcn_s_setprio(0);
        WAIT_LG0; SBAR;                      // Ps is wave-local: no s_barrier
        #pragma unroll
        for (int j = 0; j < 8; ++j) {
            const int row = j*4 + rr2;
            u32x2 d = *(const u32x2*)(PsW + row*128 + (((s8>>1) ^ (row&7))*16) + (s8&1)*8);
            f32x4 o;
            o[0]=lo2f(d[0]); o[1]=hi2f(d[0]); o[2]=lo2f(d[1]); o[3]=hi2f(d[1]);
            *(f32x4*)(abase + (size_t)row*Lc + kt*64 + s8*4) = o;
        }
        if (kt+1 < NT) {
            // drain through V(kt+1)/K(kt+1); keep K(kt+2) + 8 stores in flight
            if (kt+2 < NT) { WAIT_VM12; } else { WAIT_VM8; }
            BARRIER;
        }
    }

    #pragma unroll
    for (int r = 0; r < 16; ++r) {
        const int R = (r&3) + 8*(r>>2) + 4*hi;
        const size_t row = (size_t)bb*Lc + q0 + w*32 + R;
        ctxh[row*Dc + h*64 + ln31]      = (__bf16)ctx0[r];
        ctxh[row*Dc + h*64 + 32 + ln31] = (__bf16)ctx1[r];
    }
    #undef STAGE_K
    #undef STAGE_V
    #undef KB
    #undef VB
}

// ---------------------------------------------------------------------------
// out: ctxh(bf16) @ Wo + bo, B split hi/lo.  m97-style gload_lds + swizzle.
// ---------------------------------------------------------------------------
__global__ __launch_bounds__(256) void out_kernel(
    const __bf16* __restrict__ ctxh, const __bf16* __restrict__ Woh,
    const __bf16* __restrict__ Wol, const float* __restrict__ bo,
    float* __restrict__ out)
{
    const int m0 = blockIdx.y * 128, n0 = blockIdx.x * 128;
    const int t = threadIdx.x, lane = t & 63, w = t >> 6;
    const int wm = w >> 1, wn = w & 1;

    __shared__ __align__(16) __bf16 As[128][32];
    __shared__ __align__(16) __bf16 Bh[128][32];
    __shared__ __align__(16) __bf16 Bl[128][32];

    const int row4 = lane >> 2;
    const int scol = ((lane & 3) ^ (row4 & 3)) * 8;

    f32x4 acc[4][4] = {};

    for (int k0 = 0; k0 < Dc; k0 += 32) {
        #pragma unroll
        for (int i = 0; i < 2; ++i) {
            int row = 16*(2*w+i) + row4;
            gl_lds16(ctxh + (size_t)(m0+row)*Dc + k0 + scol, (char*)As + (2*w+i)*1024);
            gl_lds16(Woh  + (size_t)(n0+row)*Dc + k0 + scol, (char*)Bh + (2*w+i)*1024);
            gl_lds16(Wol  + (size_t)(n0+row)*Dc + k0 + scol, (char*)Bl + (2*w+i)*1024);
        }
        WAIT_VM0; __syncthreads();
        bf16x8 a[4], bh[4], bl[4];
        const int s2 = lane >> 4;
        #pragma unroll
        for (int i = 0; i < 4; ++i) {
            int Ra = wm*64 + i*16 + (lane&15);
            int Rb = wn*64 + i*16 + (lane&15);
            a[i]  = *(const bf16x8*)((const char*)&As[Ra][0] + ((s2 ^ (Ra&3))*16));
            bh[i] = *(const bf16x8*)((const char*)&Bh[Rb][0] + ((s2 ^ (Rb&3))*16));
            bl[i] = *(const bf16x8*)((const char*)&Bl[Rb][0] + ((s2 ^ (Rb&3))*16));
        }
        #pragma unroll
        for (int mi = 0; mi < 4; ++mi)
            #pragma unroll
            for (int ni = 0; ni < 4; ++ni) {
                acc[mi][ni] = __builtin_amdgcn_mfma_f32_16x16x32_bf16(a[mi], bh[ni], acc[mi][ni], 0, 0, 0);
                acc[mi][ni] = __builtin_amdgcn_mfma_f32_16x16x32_bf16(a[mi], bl[ni], acc[mi][ni], 0, 0, 0);
            }
        __syncthreads();
    }
    #pragma unroll
    for (int mi = 0; mi < 4; ++mi)
        #pragma unroll
        for (int ni = 0; ni < 4; ++ni)
            #pragma unroll
            for (int r = 0; r < 4; ++r) {
                int row = m0 + wm*64 + mi*16 + (lane>>4)*4 + r;
                int col = n0 + wn*64 + ni*16 + (lane&15);
                out[(size_t)row * Dc + col] = acc[mi][ni][r] + bo[col];
            }
}

// ---------------------------------------------------------------------------
extern "C" void kernel_launch(void* const* d_in, const int* in_sizes, int n_in,
                              void* d_out, int out_size, void* d_ws, size_t ws_size,
                              hipStream_t stream)
{
    const float* hidden = (const float*)d_in[0];
    const float* pos    = (const float*)d_in[1];
    const float* Wcq = (const float*)d_in[2];  const float* bcq = (const float*)d_in[3];
    const float* Wck = (const float*)d_in[4];  const float* bck = (const float*)d_in[5];
    const float* Wpq = (const float*)d_in[6];  const float* bpq = (const float*)d_in[7];
    const float* Wpk = (const float*)d_in[8];  const float* bpk = (const float*)d_in[9];
    const float* relb = (const float*)d_in[10];
    const float* Wo  = (const float*)d_in[11]; const float* bo  = (const float*)d_in[12];

    float* out  = (float*)d_out;
    float* attn = out + (size_t)Mc * Dc;

    // ws (bf16 elems): Woh[0,1M) Wol[1M,2M) Wt[2M,6M) (ctxh overlays Wt)
    // Qc[6M,14M) Kc[14M,22M) VT[22M,26M) badd[26M, +128K f32)  -> ~52.3 MB
    __bf16* ws   = (__bf16*)d_ws;
    __bf16* Woh  = ws;
    __bf16* Wol  = ws + (1u<<20);
    __bf16* Wt   = ws + (2u<<20);
    __bf16* ctxh = Wt;
    __bf16* Qc   = ws + (6u<<20);
    __bf16* Kc   = ws + (14u<<20);
    __bf16* VTb  = ws + (22u<<20);
    float*  badd = (float*)(ws + (26u<<20));

    prep_kernel<<<dim3(16, 8, 5), 256, 0, stream>>>(Wcq, Wck, Wpq, Wpk, Wo, Wt, Woh, Wol);
    proj_kernel<<<dim3(1024), 256, 0, stream>>>(hidden, pos, Wt, bcq, bck, bpq, bpk, Qc, Kc);
    vt_kernel<<<dim3(Lc/128, 32), 256, 0, stream>>>(Kc, VTb);
    attn1_kernel<<<dim3(512), 256, 0, stream>>>(Qc, Kc, relb, badd);
    attn2_kernel<<<dim3(512), 256, 0, stream>>>(Qc, Kc, VTb, badd, attn, ctxh);
    out_kernel<<<dim3(8, 32), 256, 0, stream>>>(ctxh, Woh, Wol, bo, out);
}

// Round 9
// 326.405 us; speedup vs baseline: 1.6583x; 1.1808x over previous
//
#include <hip/hip_runtime.h>
#include <hip/hip_bf16.h>
#include <math.h>

// RaffelAttention round 9.
// r8 structure (sync identical) + non-temporal P/out stores, raw v_exp_f32,
// rel-bias folded into MFMA acc init, 4-way partial lsum.

#define Bc 2
#define Lc 2048
#define Dc 1024
#define Hc 16
#define Mc (Bc*Lc)
#define NT 32

typedef __attribute__((ext_vector_type(8))) __bf16 bf16x8;
typedef __attribute__((ext_vector_type(4))) float f32x4;
typedef __attribute__((ext_vector_type(16))) float f32x16;
typedef __attribute__((ext_vector_type(2))) unsigned u32x2;

union U4 { unsigned u[4]; bf16x8 v; };

__device__ __forceinline__ void gl_lds16(const void* g, void* l) {
    __builtin_amdgcn_global_load_lds(
        (const __attribute__((address_space(1))) void*)g,
        (__attribute__((address_space(3))) void*)l, 16, 0, 0);
}
__device__ __forceinline__ unsigned pkbf(float a, float b) {
    unsigned short ua = __builtin_bit_cast(unsigned short, (__bf16)a);
    unsigned short ub = __builtin_bit_cast(unsigned short, (__bf16)b);
    return (unsigned)ua | ((unsigned)ub << 16);
}
__device__ __forceinline__ float lo2f(unsigned u){ return __builtin_bit_cast(float, u << 16); }
__device__ __forceinline__ float hi2f(unsigned u){ return __builtin_bit_cast(float, u & 0xffff0000u); }
#define E2(x) __builtin_amdgcn_exp2f(x)

#define WAIT_VM0  asm volatile("s_waitcnt vmcnt(0)" ::: "memory")
#define WAIT_VM4  asm volatile("s_waitcnt vmcnt(4)" ::: "memory")
#define WAIT_VM8  asm volatile("s_waitcnt vmcnt(8)" ::: "memory")
#define WAIT_VM12 asm volatile("s_waitcnt vmcnt(12)" ::: "memory")
#define WAIT_LG0  asm volatile("s_waitcnt lgkmcnt(0)" ::: "memory")
#define SBAR __builtin_amdgcn_sched_barrier(0)
#define BARRIER do { __builtin_amdgcn_sched_barrier(0); __builtin_amdgcn_s_barrier(); __builtin_amdgcn_sched_barrier(0); } while (0)

// ---------------------------------------------------------------------------
// prep: transpose weights to bf16 [n][k].  z=0..3 -> Wt[z]; z=4 -> Woh/Wol.
// ---------------------------------------------------------------------------
__global__ __launch_bounds__(256) void prep_kernel(
    const float* __restrict__ Wcq, const float* __restrict__ Wck,
    const float* __restrict__ Wpq, const float* __restrict__ Wpk,
    const float* __restrict__ Wo,
    __bf16* __restrict__ Wt, __bf16* __restrict__ Woh, __bf16* __restrict__ Wol)
{
    const int z = blockIdx.z;
    const float* W = (z==0)?Wcq:(z==1)?Wck:(z==2)?Wpq:(z==3)?Wpk:Wo;
    const int t = threadIdx.x;
    const int n  = blockIdx.x*64 + (t & 63);
    const int k0 = blockIdx.y*128 + (t >> 6)*32;
    float v[32];
    #pragma unroll
    for (int j = 0; j < 32; ++j) v[j] = W[(size_t)(k0+j)*Dc + n];
    if (z < 4) {
        __bf16* dst = Wt + (size_t)z*Dc*Dc + (size_t)n*Dc + k0;
        #pragma unroll
        for (int c = 0; c < 4; ++c) {
            bf16x8 o;
            #pragma unroll
            for (int j = 0; j < 8; ++j) o[j] = (__bf16)v[c*8+j];
            *(bf16x8*)(dst + c*8) = o;
        }
    } else {
        __bf16* dh = Woh + (size_t)n*Dc + k0;
        __bf16* dl = Wol + (size_t)n*Dc + k0;
        #pragma unroll
        for (int c = 0; c < 4; ++c) {
            bf16x8 oh, ol;
            #pragma unroll
            for (int j = 0; j < 8; ++j) {
                float x = v[c*8+j];
                __bf16 hi = (__bf16)x;
                oh[j] = hi; ol[j] = (__bf16)(x - (float)hi);
            }
            *(bf16x8*)(dh + c*8) = oh;
            *(bf16x8*)(dl + c*8) = ol;
        }
    }
}

// ---------------------------------------------------------------------------
// proj: X(fp32) @ Wt[z](bf16,[n][k]) -> Q'/K' bf16 [B,H,L,128] halves.
// ---------------------------------------------------------------------------
__global__ __launch_bounds__(256) void proj_kernel(
    const float* __restrict__ hidden, const float* __restrict__ pos,
    const __bf16* __restrict__ Wt,
    const float* __restrict__ bcq, const float* __restrict__ bck,
    const float* __restrict__ bpq, const float* __restrict__ bpk,
    __bf16* __restrict__ Qc, __bf16* __restrict__ Kc)
{
    const int g = blockIdx.x;
    const int nblk = g >> 7, sg = g & 127, mblk = sg & 31, z = sg >> 5;
    const int m0 = mblk*128, n0 = nblk*128;
    const float* X = (z < 2) ? hidden : pos;
    const __bf16* Wz = Wt + (size_t)z*Dc*Dc;
    const float* bias = (z==0)?bcq:(z==1)?bck:(z==2)?bpq:bpk;
    __bf16* dst = (z & 1) ? Kc : Qc;
    const int half = z >> 1;
    const float scale = (z & 1) ? 1.0f : 0.18033688011112042f; // 0.125*log2e on Q

    const int t = threadIdx.x, lane = t & 63, w = t >> 6;
    const int wm = w >> 1, wn = w & 1;

    __shared__ __align__(16) float  Asf[128][32];
    __shared__ __align__(16) __bf16 Bs[128][32];

    const int arowL = lane >> 3;
    const int acol  = ((lane & 7) ^ arowL) * 4;
    const int brow4 = lane >> 2;
    const int bcol  = ((lane & 3) ^ (brow4 & 3)) * 8;

    f32x4 acc[4][4] = {};

    for (int k0 = 0; k0 < Dc; k0 += 32) {
        #pragma unroll
        for (int i = 0; i < 4; ++i) {
            int row = 8*(4*w+i) + arowL;
            gl_lds16(X + (size_t)(m0+row)*Dc + k0 + acol, (char*)Asf + (4*w+i)*1024);
        }
        #pragma unroll
        for (int i = 0; i < 2; ++i) {
            int row = 16*(2*w+i) + brow4;
            gl_lds16(Wz + (size_t)(n0+row)*Dc + k0 + bcol, (char*)Bs + (2*w+i)*1024);
        }
        WAIT_VM0; __syncthreads();
        bf16x8 a[4], b[4];
        const int s2 = lane >> 4;
        #pragma unroll
        for (int i = 0; i < 4; ++i) {
            int R = wm*64 + i*16 + (lane&15);
            f32x4 x0 = *(const f32x4*)((const char*)&Asf[R][0] + (((2*s2  ) ^ (R&7))*16));
            f32x4 x1 = *(const f32x4*)((const char*)&Asf[R][0] + (((2*s2+1) ^ (R&7))*16));
            bf16x8 af;
            af[0]=(__bf16)x0[0]; af[1]=(__bf16)x0[1]; af[2]=(__bf16)x0[2]; af[3]=(__bf16)x0[3];
            af[4]=(__bf16)x1[0]; af[5]=(__bf16)x1[1]; af[6]=(__bf16)x1[2]; af[7]=(__bf16)x1[3];
            a[i] = af;
            int Rb = wn*64 + i*16 + (lane&15);
            b[i] = *(const bf16x8*)((const char*)&Bs[Rb][0] + ((s2 ^ (Rb&3))*16));
        }
        #pragma unroll
        for (int mi = 0; mi < 4; ++mi)
            #pragma unroll
            for (int ni = 0; ni < 4; ++ni)
                acc[mi][ni] = __builtin_amdgcn_mfma_f32_16x16x32_bf16(a[mi], b[ni], acc[mi][ni], 0, 0, 0);
        __syncthreads();
    }
    #pragma unroll
    for (int mi = 0; mi < 4; ++mi)
        #pragma unroll
        for (int ni = 0; ni < 4; ++ni)
            #pragma unroll
            for (int r = 0; r < 4; ++r) {
                int row = m0 + wm*64 + mi*16 + (lane>>4)*4 + r;
                int col = n0 + wn*64 + ni*16 + (lane&15);
                float v = (acc[mi][ni][r] + bias[col]) * scale;
                int bb = row >> 11, l = row & (Lc-1);
                int hh = col >> 6,  hd = col & 63;
                dst[(((size_t)bb*Hc + hh)*Lc + l)*128 + half*64 + hd] = (__bf16)v;
            }
}

// ---------------------------------------------------------------------------
// vt: VT[bh][d 0..63][l 0..2047] = Kc[bh][l][d]  (V = ck = first 64 dims)
// ---------------------------------------------------------------------------
__global__ __launch_bounds__(256) void vt_kernel(
    const __bf16* __restrict__ Kc, __bf16* __restrict__ VT)
{
    const int l0 = blockIdx.x * 128, hb = blockIdx.y;
    const int t = threadIdx.x, w = t >> 6, lane = t & 63;
    __shared__ __bf16 T[128][72];
    const __bf16* src = Kc + ((size_t)hb*Lc + l0)*128;
    {
        const int lr = t >> 3, cc = t & 7;
        #pragma unroll
        for (int j = 0; j < 4; ++j)
            *(bf16x8*)&T[lr + j*32][cc*8] = *(const bf16x8*)(src + (size_t)(lr + j*32)*128 + cc*8);
    }
    __syncthreads();
    {
        const int d = lane;
        __bf16* dstp = VT + ((size_t)hb*64 + d)*Lc + l0 + w*32;
        #pragma unroll
        for (int j = 0; j < 4; ++j) {
            bf16x8 o;
            #pragma unroll
            for (int i = 0; i < 8; ++i) o[i] = T[w*32 + j*8 + i][d];
            *(bf16x8*)(dstp + j*8) = o;
        }
    }
}

// ---------------------------------------------------------------------------
// attn1: lsum pass. bc folded into acc init; raw v_exp; 4-way partial sums.
// ---------------------------------------------------------------------------
__global__ __launch_bounds__(256, 2) void attn1_kernel(
    const __bf16* __restrict__ Qc, const __bf16* __restrict__ Kc,
    const float* __restrict__ rel_bias, float* __restrict__ baddp)
{
    const int g = blockIdx.x;
    const int qt = g >> 5, hb = g & 31, h = hb & 15;
    const int q0 = qt * 128;
    const int t = threadIdx.x, lane = t & 63, w = t >> 6;
    const int ln31 = lane & 31, hi = lane >> 5;

    const __bf16* Qp = Qc + (size_t)hb * Lc * 128;
    const __bf16* Kp = Kc + (size_t)hb * Lc * 128;

    __shared__ __align__(16) char smem[49152];   // 3 x 16KB K buffers

    bf16x8 qa[8];
    {
        const __bf16* qrow = Qp + (size_t)(q0 + w*32 + ln31) * 128 + hi*8;
        #pragma unroll
        for (int ks = 0; ks < 8; ++ks) qa[ks] = *(const bf16x8*)(qrow + ks*16);
    }

    int kof[4];
    #pragma unroll
    for (int c = 0; c < 4; ++c) {
        int rl = c*4 + (lane >> 4);
        int rr = w*16 + rl;
        kof[c] = rr*128 + (((lane & 15) ^ rl) * 8);
    }
    int kR[8];
    #pragma unroll
    for (int ks = 0; ks < 8; ++ks) kR[ks] = ((ks*2 + hi) ^ (lane & 15)) * 8;

    #define STAGE_K(B, KT) do { \
        const __bf16* kb_ = Kp + (size_t)(KT)*8192; \
        gl_lds16(kb_ + kof[0], smem + ((B)*64 + w*16 +  0)*256); \
        gl_lds16(kb_ + kof[1], smem + ((B)*64 + w*16 +  4)*256); \
        gl_lds16(kb_ + kof[2], smem + ((B)*64 + w*16 +  8)*256); \
        gl_lds16(kb_ + kof[3], smem + ((B)*64 + w*16 + 12)*256); \
    } while (0)
    #define KB(B, ROW, KS) (*(const bf16x8*)(smem + ((B)*64 + (ROW))*256 + kR[KS]*2))

    const float bc = rel_bias[h] * 0.18033688011112042f;
    float lp[4] = {0.f, 0.f, 0.f, 0.f};

    STAGE_K(0, 0); STAGE_K(1, 1);
    WAIT_VM4; BARRIER;
    for (int kt = 0; kt < NT; ++kt) {
        if (kt+2 < NT) STAGE_K((kt+2) % 3, kt+2);
        SBAR;
        const int buf = kt % 3;
        f32x16 s0, s1;
        #pragma unroll
        for (int r = 0; r < 16; ++r) { s0[r] = bc; s1[r] = bc; }  // bias via C-in
        __builtin_amdgcn_s_setprio(1);
        #pragma unroll
        for (int ks = 0; ks < 8; ++ks) {
            bf16x8 kb0 = KB(buf, ln31, ks);
            bf16x8 kb1 = KB(buf, 32 + ln31, ks);
            s0 = __builtin_amdgcn_mfma_f32_32x32x16_bf16(kb0, qa[ks], s0, 0, 0, 0);
            s1 = __builtin_amdgcn_mfma_f32_32x32x16_bf16(kb1, qa[ks], s1, 0, 0, 0);
        }
        __builtin_amdgcn_s_setprio(0);
        #pragma unroll
        for (int r = 0; r < 16; ++r) {
            lp[r & 3] += E2(s0[r]);
            lp[r & 3] += E2(s1[r]);
        }
        if (kt+2 < NT) { WAIT_VM4; } else { WAIT_VM0; }
        BARRIER;
    }
    float lsum = (lp[0] + lp[1]) + (lp[2] + lp[3]);
    lsum += __shfl_xor(lsum, 32);
    if (!hi) baddp[(size_t)hb*Lc + q0 + w*32 + ln31] = bc - log2f(lsum);
    #undef STAGE_K
    #undef KB
}

// ---------------------------------------------------------------------------
// attn2: P out + PV. badd folded into acc init; raw v_exp; non-temporal
// P stores. Sync identical to r8 (verified).
// ---------------------------------------------------------------------------
__global__ __launch_bounds__(256, 2) void attn2_kernel(
    const __bf16* __restrict__ Qc, const __bf16* __restrict__ Kc,
    const __bf16* __restrict__ VT, const float* __restrict__ baddp,
    float* __restrict__ attn, __bf16* __restrict__ ctxh)
{
    const int g = blockIdx.x;
    const int qt = g >> 5, hb = g & 31, h = hb & 15, bb = hb >> 4;
    const int q0 = qt * 128;
    const int t = threadIdx.x, lane = t & 63, w = t >> 6;
    const int ln31 = lane & 31, hi = lane >> 5;

    const __bf16* Qp = Qc + (size_t)hb * Lc * 128;
    const __bf16* Kp = Kc + (size_t)hb * Lc * 128;
    const __bf16* Vp = VT + (size_t)hb * 64 * Lc;

    // LDS: K 3x16KB @0 | V 2x8KB @49152 | Ps 4x4KB @65536   = 80KB
    __shared__ __align__(16) char smem[81920];
    char* const VsB = smem + 49152;
    char* const PsW = smem + 65536 + w*4096;

    bf16x8 qa[8];
    {
        const __bf16* qrow = Qp + (size_t)(q0 + w*32 + ln31) * 128 + hi*8;
        #pragma unroll
        for (int ks = 0; ks < 8; ++ks) qa[ks] = *(const bf16x8*)(qrow + ks*16);
    }
    const float badd = baddp[(size_t)hb*Lc + q0 + w*32 + ln31];

    int kof[4];
    #pragma unroll
    for (int c = 0; c < 4; ++c) {
        int rl = c*4 + (lane >> 4);
        int rr = w*16 + rl;
        kof[c] = rr*128 + (((lane & 15) ^ rl) * 8);
    }
    int vof[2];
    #pragma unroll
    for (int c = 0; c < 2; ++c) {
        int dl = lane >> 3;
        int dd = w*16 + c*8 + dl;
        vof[c] = dd*2048 + (((lane & 7) ^ dl) * 8);
    }
    int kR[8];
    #pragma unroll
    for (int ks = 0; ks < 8; ++ks) kR[ks] = ((ks*2 + hi) ^ (lane & 15)) * 8;
    int vR[4];
    #pragma unroll
    for (int ks = 0; ks < 4; ++ks) vR[ks] = ((ks*2 + hi) ^ (lane & 7)) * 8;

    #define STAGE_K(B, KT) do { \
        const __bf16* kb_ = Kp + (size_t)(KT)*8192; \
        gl_lds16(kb_ + kof[0], smem + ((B)*64 + w*16 +  0)*256); \
        gl_lds16(kb_ + kof[1], smem + ((B)*64 + w*16 +  4)*256); \
        gl_lds16(kb_ + kof[2], smem + ((B)*64 + w*16 +  8)*256); \
        gl_lds16(kb_ + kof[3], smem + ((B)*64 + w*16 + 12)*256); \
    } while (0)
    #define STAGE_V(B, KT) do { \
        const __bf16* vb_ = Vp + (KT)*64; \
        gl_lds16(vb_ + vof[0], VsB + ((B)*64 + w*16 + 0)*128); \
        gl_lds16(vb_ + vof[1], VsB + ((B)*64 + w*16 + 8)*128); \
    } while (0)
    #define KB(B, ROW, KS) (*(const bf16x8*)(smem + ((B)*64 + (ROW))*256 + kR[KS]*2))
    #define VB(B, ROW, KS) (*(const bf16x8*)(VsB  + ((B)*64 + (ROW))*128 + vR[KS]*2))

    f32x16 ctx0 = {}, ctx1 = {};
    float* abase = attn + ((size_t)hb*Lc + q0 + w*32)*Lc;
    const int rr2 = lane >> 4;
    const int s8  = lane & 15;

    STAGE_K(0, 0); STAGE_V(0, 0); STAGE_K(1, 1);
    WAIT_VM4; BARRIER;

    for (int kt = 0; kt < NT; ++kt) {
        if (kt+1 < NT) STAGE_V((kt+1) & 1, kt+1);
        if (kt+2 < NT) STAGE_K((kt+2) % 3, kt+2);
        SBAR;
        const int buf = kt % 3;
        f32x16 s0, s1;
        #pragma unroll
        for (int r = 0; r < 16; ++r) { s0[r] = badd; s1[r] = badd; }  // via C-in
        __builtin_amdgcn_s_setprio(1);
        #pragma unroll
        for (int ks = 0; ks < 8; ++ks) {
            bf16x8 kb0 = KB(buf, ln31, ks);
            bf16x8 kb1 = KB(buf, 32 + ln31, ks);
            s0 = __builtin_amdgcn_mfma_f32_32x32x16_bf16(kb0, qa[ks], s0, 0, 0, 0);
            s1 = __builtin_amdgcn_mfma_f32_32x32x16_bf16(kb1, qa[ks], s1, 0, 0, 0);
        }
        __builtin_amdgcn_s_setprio(0);
        // p = exp2(s); pack pairs; exchange hi/lo kv halves
        unsigned u0[8], u1[8], r0[8], r1[8];
        #pragma unroll
        for (int gq = 0; gq < 4; ++gq) {
            u0[gq]   = pkbf(E2(s0[4*gq+0]), E2(s0[4*gq+1]));
            u1[gq]   = pkbf(E2(s0[4*gq+2]), E2(s0[4*gq+3]));
            u0[4+gq] = pkbf(E2(s1[4*gq+0]), E2(s1[4*gq+1]));
            u1[4+gq] = pkbf(E2(s1[4*gq+2]), E2(s1[4*gq+3]));
        }
        #pragma unroll
        for (int gq = 0; gq < 8; ++gq) {
            r0[gq] = __shfl_xor(u0[gq], 32);
            r1[gq] = __shfl_xor(u1[gq], 32);
        }
        bf16x8 pb[4];
        #pragma unroll
        for (int ks = 0; ks < 4; ++ks) {
            const int gq = 2*ks + hi;
            U4 u;
            u.u[0] = hi ? r0[gq] : u0[gq];
            u.u[1] = hi ? r1[gq] : u1[gq];
            u.u[2] = hi ? u0[gq] : r0[gq];
            u.u[3] = hi ? u1[gq] : r1[gq];
            pb[ks] = u.v;
            *(bf16x8*)(PsW + ln31*128 + ((gq ^ (ln31 & 7))*16)) = u.v;
        }
        __builtin_amdgcn_s_setprio(1);
        #pragma unroll
        for (int ks = 0; ks < 4; ++ks) {
            bf16x8 v0 = VB(kt & 1, ln31, ks);
            bf16x8 v1 = VB(kt & 1, 32 + ln31, ks);
            ctx0 = __builtin_amdgcn_mfma_f32_32x32x16_bf16(pb[ks], v0, ctx0, 0, 0, 0);
            ctx1 = __builtin_amdgcn_mfma_f32_32x32x16_bf16(pb[ks], v1, ctx1, 0, 0, 0);
        }
        __builtin_amdgcn_s_setprio(0);
        WAIT_LG0; SBAR;
        #pragma unroll
        for (int j = 0; j < 8; ++j) {
            const int row = j*4 + rr2;
            u32x2 d = *(const u32x2*)(PsW + row*128 + (((s8>>1) ^ (row&7))*16) + (s8&1)*8);
            f32x4 o;
            o[0]=lo2f(d[0]); o[1]=hi2f(d[0]); o[2]=lo2f(d[1]); o[3]=hi2f(d[1]);
            __builtin_nontemporal_store(o, (f32x4*)(abase + (size_t)row*Lc + kt*64 + s8*4));
        }
        if (kt+1 < NT) {
            if (kt+2 < NT) { WAIT_VM12; } else { WAIT_VM8; }
            BARRIER;
        }
    }

    #pragma unroll
    for (int r = 0; r < 16; ++r) {
        const int R = (r&3) + 8*(r>>2) + 4*hi;
        const size_t row = (size_t)bb*Lc + q0 + w*32 + R;
        ctxh[row*Dc + h*64 + ln31]      = (__bf16)ctx0[r];
        ctxh[row*Dc + h*64 + 32 + ln31] = (__bf16)ctx1[r];
    }
    #undef STAGE_K
    #undef STAGE_V
    #undef KB
    #undef VB
}

// ---------------------------------------------------------------------------
// out: ctxh(bf16) @ Wo + bo, B split hi/lo.  Non-temporal result stores.
// ---------------------------------------------------------------------------
__global__ __launch_bounds__(256) void out_kernel(
    const __bf16* __restrict__ ctxh, const __bf16* __restrict__ Woh,
    const __bf16* __restrict__ Wol, const float* __restrict__ bo,
    float* __restrict__ out)
{
    const int m0 = blockIdx.y * 128, n0 = blockIdx.x * 128;
    const int t = threadIdx.x, lane = t & 63, w = t >> 6;
    const int wm = w >> 1, wn = w & 1;

    __shared__ __align__(16) __bf16 As[128][32];
    __shared__ __align__(16) __bf16 Bh[128][32];
    __shared__ __align__(16) __bf16 Bl[128][32];

    const int row4 = lane >> 2;
    const int scol = ((lane & 3) ^ (row4 & 3)) * 8;

    f32x4 acc[4][4] = {};

    for (int k0 = 0; k0 < Dc; k0 += 32) {
        #pragma unroll
        for (int i = 0; i < 2; ++i) {
            int row = 16*(2*w+i) + row4;
            gl_lds16(ctxh + (size_t)(m0+row)*Dc + k0 + scol, (char*)As + (2*w+i)*1024);
            gl_lds16(Woh  + (size_t)(n0+row)*Dc + k0 + scol, (char*)Bh + (2*w+i)*1024);
            gl_lds16(Wol  + (size_t)(n0+row)*Dc + k0 + scol, (char*)Bl + (2*w+i)*1024);
        }
        WAIT_VM0; __syncthreads();
        bf16x8 a[4], bh[4], bl[4];
        const int s2 = lane >> 4;
        #pragma unroll
        for (int i = 0; i < 4; ++i) {
            int Ra = wm*64 + i*16 + (lane&15);
            int Rb = wn*64 + i*16 + (lane&15);
            a[i]  = *(const bf16x8*)((const char*)&As[Ra][0] + ((s2 ^ (Ra&3))*16));
            bh[i] = *(const bf16x8*)((const char*)&Bh[Rb][0] + ((s2 ^ (Rb&3))*16));
            bl[i] = *(const bf16x8*)((const char*)&Bl[Rb][0] + ((s2 ^ (Rb&3))*16));
        }
        #pragma unroll
        for (int mi = 0; mi < 4; ++mi)
            #pragma unroll
            for (int ni = 0; ni < 4; ++ni) {
                acc[mi][ni] = __builtin_amdgcn_mfma_f32_16x16x32_bf16(a[mi], bh[ni], acc[mi][ni], 0, 0, 0);
                acc[mi][ni] = __builtin_amdgcn_mfma_f32_16x16x32_bf16(a[mi], bl[ni], acc[mi][ni], 0, 0, 0);
            }
        __syncthreads();
    }
    #pragma unroll
    for (int mi = 0; mi < 4; ++mi)
        #pragma unroll
        for (int ni = 0; ni < 4; ++ni)
            #pragma unroll
            for (int r = 0; r < 4; ++r) {
                int row = m0 + wm*64 + mi*16 + (lane>>4)*4 + r;
                int col = n0 + wn*64 + ni*16 + (lane&15);
                __builtin_nontemporal_store(acc[mi][ni][r] + bo[col],
                                            out + (size_t)row * Dc + col);
            }
}

// ---------------------------------------------------------------------------
extern "C" void kernel_launch(void* const* d_in, const int* in_sizes, int n_in,
                              void* d_out, int out_size, void* d_ws, size_t ws_size,
                              hipStream_t stream)
{
    const float* hidden = (const float*)d_in[0];
    const float* pos    = (const float*)d_in[1];
    const float* Wcq = (const float*)d_in[2];  const float* bcq = (const float*)d_in[3];
    const float* Wck = (const float*)d_in[4];  const float* bck = (const float*)d_in[5];
    const float* Wpq = (const float*)d_in[6];  const float* bpq = (const float*)d_in[7];
    const float* Wpk = (const float*)d_in[8];  const float* bpk = (const float*)d_in[9];
    const float* relb = (const float*)d_in[10];
    const float* Wo  = (const float*)d_in[11]; const float* bo  = (const float*)d_in[12];

    float* out  = (float*)d_out;
    float* attn = out + (size_t)Mc * Dc;

    __bf16* ws   = (__bf16*)d_ws;
    __bf16* Woh  = ws;
    __bf16* Wol  = ws + (1u<<20);
    __bf16* Wt   = ws + (2u<<20);
    __bf16* ctxh = Wt;
    __bf16* Qc   = ws + (6u<<20);
    __bf16* Kc   = ws + (14u<<20);
    __bf16* VTb  = ws + (22u<<20);
    float*  badd = (float*)(ws + (26u<<20));

    prep_kernel<<<dim3(16, 8, 5), 256, 0, stream>>>(Wcq, Wck, Wpq, Wpk, Wo, Wt, Woh, Wol);
    proj_kernel<<<dim3(1024), 256, 0, stream>>>(hidden, pos, Wt, bcq, bck, bpq, bpk, Qc, Kc);
    vt_kernel<<<dim3(Lc/128, 32), 256, 0, stream>>>(Kc, VTb);
    attn1_kernel<<<dim3(512), 256, 0, stream>>>(Qc, Kc, relb, badd);
    attn2_kernel<<<dim3(512), 256, 0, stream>>>(Qc, Kc, VTb, badd, attn, ctxh);
    out_kernel<<<dim3(8, 32), 256, 0, stream>>>(ctxh, Woh, Wol, bo, out);
}